// Round 10
// baseline (249.742 us; speedup 1.0000x reference)
//
#include <hip/hip_runtime.h>

// GAT forward, MI355X. Round 9: abandon exp-factorization (2 failed rounds,
// R8 absmax 0.113 unexplained); attn_mfma restored to the twice-passing R5
// inner loop (direct __expf + truncate, within-iter load-first, no reg-dbuf).
// Keeps: separate pack_adj, split-K gemmT_sk, packed h^T, merged cvt.
// B=8, N=1024, F=256, O=128, H=8, HO=1024, BH=64.
//
// h^T packed layout per (b,h): elem (j,o) at (j>>3)*1024 + o*8 + (j&7).
//
// ws floats:
//   out2 [8192,128] @ 0        (1,048,576)
//   s1 @ 1048576  s2 @ 1114112 (65,536 each)
//   s1o @ 1179648 s2o @ 1187840 (8,192 each)
// ushort region @ float offset 1196032:
//   x_b     [8,1024,1024] @ 0         h_catTb @ 8388608   h2Tb @ 16777216
//   W_attTb @ 17825792    W_outTb @ 18087936
//   lin_wb  @ 18219008    ln_wb   @ 18350080
//   adjp (ull[8192*16]) @ ushort 18366464  (1 MB)

#define NN 1024
#define FF 256
#define OO 128
#define HH 8
#define HO 1024

typedef __attribute__((ext_vector_type(8))) short short8;
typedef __attribute__((ext_vector_type(4))) float floatx4;

__device__ __forceinline__ ushort f2b(float f) {
    union { float f; unsigned u; } v; v.f = f;
    unsigned r = v.u + 0x7FFFu + ((v.u >> 16) & 1u);   // RNE
    return (ushort)(r >> 16);
}

// ---------------- adj int32 -> bitmask (standalone; 8192 waves, BW-bound) ---
__global__ __launch_bounds__(256) void pack_adj(
    const int* __restrict__ adj, unsigned long long* __restrict__ adjp)
{
    int w = blockIdx.x * 4 + (threadIdx.x >> 6);   // row 0..8191 (= b*N+i)
    int lane = threadIdx.x & 63;
    const int* row = adj + (long)w * NN;
#pragma unroll
    for (int it = 0; it < 16; it++) {
        unsigned long long m = __ballot(row[it * 64 + lane] > 0);
        if (lane == 0) adjp[(long)w * 16 + it] = m;
    }
}

// ---------------- transpose + bf16 cvt: dst[z][c][r] = src[z][r][c] ----------
__global__ __launch_bounds__(256) void transpose_cvt(
    const float* __restrict__ src, ushort* __restrict__ dst, int R, int C)
{
    __shared__ float tile[64][65];
    int r0 = blockIdx.x * 64, c0 = blockIdx.y * 64;
    src += (long)blockIdx.z * R * C;
    dst += (long)blockIdx.z * R * C;
    int t = threadIdx.x;
    int lr = t >> 4, lc = (t & 15) * 4;
#pragma unroll
    for (int p = 0; p < 4; p++) {
        float4 v = *(const float4*)(src + (long)(r0 + p * 16 + lr) * C + c0 + lc);
        tile[p * 16 + lr][lc] = v.x; tile[p * 16 + lr][lc + 1] = v.y;
        tile[p * 16 + lr][lc + 2] = v.z; tile[p * 16 + lr][lc + 3] = v.w;
    }
    __syncthreads();
    int c = t >> 2, rq = (t & 3) * 16;
    union { ushort s[16]; uint4 q[2]; } u;
#pragma unroll
    for (int k = 0; k < 16; k++) u.s[k] = f2b(tile[rq + k][c]);
    uint4* dp = (uint4*)(dst + (long)(c0 + c) * R + r0 + rq);
    dp[0] = u.q[0]; dp[1] = u.q[1];
}

// ---------------- merged fp32->bf16 cvt for lin_w (131072) + ln_w (16384) ---
__global__ __launch_bounds__(256) void cvt_bf16_2(
    const float* __restrict__ s0, ushort* __restrict__ d0, long n0,
    const float* __restrict__ s1, ushort* __restrict__ d1)
{
    long i = ((long)blockIdx.x * 256 + threadIdx.x) * 8;
    const float* src; ushort* dst; long off;
    if (i < n0) { src = s0; dst = d0; off = i; }
    else        { src = s1; dst = d1; off = i - n0; }
    float4 v0 = *(const float4*)(src + off);
    float4 v1 = *(const float4*)(src + off + 4);
    union { ushort s[8]; uint4 q; } u;
    u.s[0] = f2b(v0.x); u.s[1] = f2b(v0.y); u.s[2] = f2b(v0.z); u.s[3] = f2b(v0.w);
    u.s[4] = f2b(v1.x); u.s[5] = f2b(v1.y); u.s[6] = f2b(v1.z); u.s[7] = f2b(v1.w);
    *(uint4*)(dst + off) = u.q;
}

// ---------------- layer-0: bf16 MFMA "NT" GEMM, packed-h^T out, fused dots --
__global__ __launch_bounds__(256) void gemmT(
    const ushort* __restrict__ AT, const float* __restrict__ Bf,
    ushort* __restrict__ Cb, float* __restrict__ s1, float* __restrict__ s2,
    const float* __restrict__ a1g, const float* __restrict__ a2g,
    int K, int Hh)
{
    int t = threadIdx.x;
    int wave = t >> 6, lane = t & 63;
    int quad = lane >> 4, l16 = lane & 15;
    int bh = blockIdx.y;
    int hh = bh % Hh, b = bh / Hh;
    int n0w = blockIdx.x * 64 + wave * 16;

    const ushort* A = AT + (long)hh * OO * K;
    const float* browf = Bf + ((long)b * NN + n0w + l16) * K;

    floatx4 acc[8];
    floatx4 zero = {0.f, 0.f, 0.f, 0.f};
#pragma unroll
    for (int mt = 0; mt < 8; mt++) acc[mt] = zero;

    for (int k0 = 0; k0 < K; k0 += 32) {
        int kb = k0 + quad * 8;
        float4 b0 = *(const float4*)(browf + kb);
        float4 b1 = *(const float4*)(browf + kb + 4);
        short8 bfr;
        bfr[0] = (short)f2b(b0.x); bfr[1] = (short)f2b(b0.y);
        bfr[2] = (short)f2b(b0.z); bfr[3] = (short)f2b(b0.w);
        bfr[4] = (short)f2b(b1.x); bfr[5] = (short)f2b(b1.y);
        bfr[6] = (short)f2b(b1.z); bfr[7] = (short)f2b(b1.w);
#pragma unroll
        for (int mt = 0; mt < 8; mt++) {
            short8 af = *(const short8*)(A + (long)(mt * 16 + l16) * K + kb);
            acc[mt] = __builtin_amdgcn_mfma_f32_16x16x32_bf16(af, bfr, acc[mt], 0, 0, 0);
        }
    }

    const float* a1 = a1g + hh * OO;
    const float* a2 = a2g + hh * OO;
    float sp1 = 0.f, sp2 = 0.f;
#pragma unroll
    for (int mt = 0; mt < 8; mt++) {
        float4 v1 = *(const float4*)(a1 + mt * 16 + quad * 4);
        float4 v2 = *(const float4*)(a2 + mt * 16 + quad * 4);
        sp1 += acc[mt][0] * v1.x + acc[mt][1] * v1.y + acc[mt][2] * v1.z + acc[mt][3] * v1.w;
        sp2 += acc[mt][0] * v2.x + acc[mt][1] * v2.y + acc[mt][2] * v2.z + acc[mt][3] * v2.w;
    }
    sp1 += __shfl_xor(sp1, 16); sp1 += __shfl_xor(sp1, 32);
    sp2 += __shfl_xor(sp2, 16); sp2 += __shfl_xor(sp2, 32);
    if (lane < 16) {
        s1[(long)bh * NN + n0w + l16] = sp1;
        s2[(long)bh * NN + n0w + l16] = sp2;
    }

    // store h^T bf16, fragment-packed: (o,n) -> (n>>3)*1024 + o*8 + (n&7)
    ushort* cb = Cb + (long)bh * OO * NN;
    int n = n0w + l16;
    int base = (n >> 3) * 1024 + (n & 7);
#pragma unroll
    for (int mt = 0; mt < 8; mt++) {
#pragma unroll
        for (int reg = 0; reg < 4; reg++) {
            int o = mt * 16 + quad * 4 + reg;
            cb[base + o * 8] = f2b(acc[mt][reg]);
        }
    }
}

// ---------------- layer-1: split-K bf16 MFMA GEMM + LDS reduce + fused dots -
__global__ __launch_bounds__(256) void gemmT_sk(
    const ushort* __restrict__ AT,    // W_outTb [128][1024]
    const ushort* __restrict__ Bb,    // x_b [8192][1024]
    ushort* __restrict__ Cb,          // h2^T packed per b
    float* __restrict__ s1, float* __restrict__ s2,
    const float* __restrict__ a1g, const float* __restrict__ a2g)
{
    __shared__ float red[4 * 2304];   // [wave][o*18 + nl], 36,864 B
    int t = threadIdx.x;
    int wave = t >> 6, lane = t & 63;
    int quad = lane >> 4, l16 = lane & 15;
    int b = blockIdx.y;
    int n0 = blockIdx.x * 16;

    const ushort* brow = Bb + ((long)b * NN + n0 + l16) * HO;
    int kbase = wave * 256;

    floatx4 acc[8];
    floatx4 zero = {0.f, 0.f, 0.f, 0.f};
#pragma unroll
    for (int mt = 0; mt < 8; mt++) acc[mt] = zero;

    for (int k0 = 0; k0 < 256; k0 += 32) {
        int kb = kbase + k0 + quad * 8;
        short8 bfr = *(const short8*)(brow + kb);
#pragma unroll
        for (int mt = 0; mt < 8; mt++) {
            short8 af = *(const short8*)(AT + (long)(mt * 16 + l16) * HO + kb);
            acc[mt] = __builtin_amdgcn_mfma_f32_16x16x32_bf16(af, bfr, acc[mt], 0, 0, 0);
        }
    }

#pragma unroll
    for (int mt = 0; mt < 8; mt++)
#pragma unroll
        for (int reg = 0; reg < 4; reg++)
            red[wave * 2304 + (mt * 16 + quad * 4 + reg) * 18 + l16] = acc[mt][reg];
    __syncthreads();

    int nl = t & 15, g = t >> 4, o0 = g * 8;
    float s[8];
#pragma unroll
    for (int k = 0; k < 8; k++) {
        int idx = (o0 + k) * 18 + nl;
        s[k] = red[idx] + red[2304 + idx] + red[4608 + idx] + red[6912 + idx];
    }

    float p1 = 0.f, p2 = 0.f;
#pragma unroll
    for (int k = 0; k < 8; k++) {
        p1 += s[k] * a1g[o0 + k];
        p2 += s[k] * a2g[o0 + k];
    }

    ushort* cb = Cb + (long)b * OO * NN;
    int nglob = n0 + nl;
    int base = (nglob >> 3) * 1024 + (nglob & 7);
#pragma unroll
    for (int k = 0; k < 8; k++) cb[base + (o0 + k) * 8] = f2b(s[k]);

    __syncthreads();
    red[g * 16 + nl] = p1;
    red[256 + g * 16 + nl] = p2;
    __syncthreads();
    if (t < 16) {
        float q1 = 0.f, q2 = 0.f;
#pragma unroll
        for (int gg = 0; gg < 16; gg++) {
            q1 += red[gg * 16 + t];
            q2 += red[256 + gg * 16 + t];
        }
        s1[(long)b * NN + n0 + t] = q1;
        s2[(long)b * NN + n0 + t] = q2;
    }
}

// ---------------- single-pass masked-softmax attention + MFMA PV ------------
// e^(i,j) = adjbit ? exp(lrelu(s1_i+s2_j)) : 0 (bounded logits, no max-sub).
// R5 inner loop (twice-passed): within-iter load-first, direct __expf,
// truncate-to-bf16. No reg-dbuf (R6's cost VGPR 108 + 32 v_mov/iter).
// JS=2 (layer 0): 4 waves = 2 i-groups(32 i) x 2 j-halves(512 j); LDS reduce.
// JS=4 (layer 1): 4 waves share one 16-i tile, 256 j each; LDS reduce.
// dyn LDS: s2s[1024] | red[8448] (stride 132) | Lred[64]  = 38,144 B
template <int JS>
__global__ __launch_bounds__(256) void attn_mfma(
    const float* __restrict__ s1g, const float* __restrict__ s2g,
    const ushort* __restrict__ hTp, const uint* __restrict__ adjp,
    float* __restrict__ outf, ushort* __restrict__ outb,
    int Hh, int outStride, int doElu, int writeBf)
{
    extern __shared__ float smem_f[];
    float* s2s = smem_f;
    float* red = smem_f + NN;
    float* Lred = red + 8448;

    int t = threadIdx.x;
    int wave = t >> 6, lane = t & 63;
    int quad = lane >> 4, l16 = lane & 15;
    int bh = blockIdx.y;
    int hh = bh % Hh, b = bh / Hh;

    const float* s2r = s2g + (long)bh * NN;
    for (int j = t; j < NN; j += 256) s2s[j] = s2r[j];
    __syncthreads();

    const ushort* hT = hTp + (long)bh * OO * NN;
    const ushort* hbase = hT + quad * 1024 + l16 * 8;
    floatx4 zero = {0.f, 0.f, 0.f, 0.f};

    if (JS == 2) {
        int ig = wave >> 1, jh = wave & 1;
        int i0 = blockIdx.x * 64 + ig * 32;
        int j_lo = jh * (NN / 2), j_hi = j_lo + NN / 2;

        float s1a = s1g[(long)bh * NN + i0 + l16];
        float s1b = s1g[(long)bh * NN + i0 + 16 + l16];
        const uint* abA = adjp + ((long)b * NN + i0 + l16) * 32;
        const uint* abB = abA + 16 * 32;

        floatx4 acc0[8], acc1[8];
#pragma unroll
        for (int ot = 0; ot < 8; ot++) { acc0[ot] = zero; acc1[ot] = zero; }
        float Lp0 = 0.f, Lp1 = 0.f;

        for (int j0 = j_lo; j0 < j_hi; j0 += 32) {
            const ushort* hp = hbase + (j0 >> 3) * 1024;
            short8 bf[8];
#pragma unroll
            for (int ot = 0; ot < 8; ot++)
                bf[ot] = *(const short8*)(hp + ot * 128);
            uint mbA = (abA[j0 >> 5] >> (quad * 8)) & 0xffu;
            uint mbB = (abB[j0 >> 5] >> (quad * 8)) & 0xffu;
            int kb = j0 + quad * 8;
            float4 sA4 = *(const float4*)(s2s + kb);
            float4 sB4 = *(const float4*)(s2s + kb + 4);
            float se[8] = {sA4.x, sA4.y, sA4.z, sA4.w, sB4.x, sB4.y, sB4.z, sB4.w};
            short8 afA, afB;
#pragma unroll
            for (int e = 0; e < 8; e++) {
                float ea = s1a + se[e]; ea = fmaxf(ea, 0.2f * ea);
                float eb = s1b + se[e]; eb = fmaxf(eb, 0.2f * eb);
                union { float f; uint u; } wa, wb;
                wa.f = ((mbA >> e) & 1u) ? __expf(ea) : 0.f;
                wb.f = ((mbB >> e) & 1u) ? __expf(eb) : 0.f;
                wa.u &= 0xffff0000u; wb.u &= 0xffff0000u;   // truncate to bf16
                afA[e] = (short)(wa.u >> 16);
                afB[e] = (short)(wb.u >> 16);
                Lp0 += wa.f; Lp1 += wb.f;
            }
#pragma unroll
            for (int ot = 0; ot < 8; ot++) {
                acc0[ot] = __builtin_amdgcn_mfma_f32_16x16x32_bf16(afA, bf[ot], acc0[ot], 0, 0, 0);
                acc1[ot] = __builtin_amdgcn_mfma_f32_16x16x32_bf16(afB, bf[ot], acc1[ot], 0, 0, 0);
            }
        }

        Lp0 += __shfl_xor(Lp0, 16); Lp0 += __shfl_xor(Lp0, 32);
        Lp1 += __shfl_xor(Lp1, 16); Lp1 += __shfl_xor(Lp1, 32);

        if (jh == 1) {
#pragma unroll
            for (int ot = 0; ot < 8; ot++)
#pragma unroll
                for (int reg = 0; reg < 4; reg++) {
                    red[(ig * 32 + quad * 4 + reg) * 132 + ot * 16 + l16] = acc0[ot][reg];
                    red[(ig * 32 + 16 + quad * 4 + reg) * 132 + ot * 16 + l16] = acc1[ot][reg];
                }
            if (lane < 16) {
                Lred[(ig * 2 + 0) * 16 + l16] = Lp0;
                Lred[(ig * 2 + 1) * 16 + l16] = Lp1;
            }
        }
        __syncthreads();
        if (jh == 0) {
            float r0 = 1.0f / (Lp0 + Lred[(ig * 2 + 0) * 16 + l16]);
            float r1 = 1.0f / (Lp1 + Lred[(ig * 2 + 1) * 16 + l16]);
#pragma unroll
            for (int tile = 0; tile < 2; tile++) {
                float rv = tile ? r1 : r0;
                floatx4* ac = tile ? acc1 : acc0;
#pragma unroll
                for (int reg = 0; reg < 4; reg++) {
                    float linv = __shfl(rv, quad * 4 + reg);
                    int rloc = ig * 32 + tile * 16 + quad * 4 + reg;
                    int row = blockIdx.x * 64 + rloc;
                    if (writeBf) {
                        ushort* orow = outb + (long)b * NN * outStride + hh * OO +
                                       (long)row * outStride + l16;
#pragma unroll
                        for (int ot = 0; ot < 8; ot++) {
                            float v = (ac[ot][reg] + red[rloc * 132 + ot * 16 + l16]) * linv;
                            if (doElu) v = (v > 0.f) ? v : (__expf(v) - 1.0f);
                            orow[ot * 16] = f2b(v);
                        }
                    } else {
                        float* orow = outf + (long)b * NN * outStride + hh * OO +
                                      (long)row * outStride + l16;
#pragma unroll
                        for (int ot = 0; ot < 8; ot++) {
                            float v = (ac[ot][reg] + red[rloc * 132 + ot * 16 + l16]) * linv;
                            if (doElu) v = (v > 0.f) ? v : (__expf(v) - 1.0f);
                            orow[ot * 16] = v;
                        }
                    }
                }
            }
        }
    } else {   // JS == 4
        int i0 = blockIdx.x * 16;
        int j_lo = wave * (NN / 4), j_hi = j_lo + NN / 4;

        float s1a = s1g[(long)bh * NN + i0 + l16];
        const uint* abA = adjp + ((long)b * NN + i0 + l16) * 32;

        floatx4 acc[8];
#pragma unroll
        for (int ot = 0; ot < 8; ot++) acc[ot] = zero;
        float Lp = 0.f;

        for (int j0 = j_lo; j0 < j_hi; j0 += 32) {
            const ushort* hp = hbase + (j0 >> 3) * 1024;
            short8 bf[8];
#pragma unroll
            for (int ot = 0; ot < 8; ot++)
                bf[ot] = *(const short8*)(hp + ot * 128);
            uint mbA = (abA[j0 >> 5] >> (quad * 8)) & 0xffu;
            int kb = j0 + quad * 8;
            float4 sA4 = *(const float4*)(s2s + kb);
            float4 sB4 = *(const float4*)(s2s + kb + 4);
            float se[8] = {sA4.x, sA4.y, sA4.z, sA4.w, sB4.x, sB4.y, sB4.z, sB4.w};
            short8 afA;
#pragma unroll
            for (int e = 0; e < 8; e++) {
                float ea = s1a + se[e]; ea = fmaxf(ea, 0.2f * ea);
                union { float f; uint u; } wa;
                wa.f = ((mbA >> e) & 1u) ? __expf(ea) : 0.f;
                wa.u &= 0xffff0000u;
                afA[e] = (short)(wa.u >> 16);
                Lp += wa.f;
            }
#pragma unroll
            for (int ot = 0; ot < 8; ot++)
                acc[ot] = __builtin_amdgcn_mfma_f32_16x16x32_bf16(afA, bf[ot], acc[ot], 0, 0, 0);
        }

        Lp += __shfl_xor(Lp, 16); Lp += __shfl_xor(Lp, 32);
#pragma unroll
        for (int ot = 0; ot < 8; ot++)
#pragma unroll
            for (int reg = 0; reg < 4; reg++)
                red[(wave * 16 + quad * 4 + reg) * 132 + ot * 16 + l16] = acc[ot][reg];
        if (lane < 16) Lred[wave * 16 + l16] = Lp;
        __syncthreads();
        int row = t >> 4, c0 = (t & 15) * 8;
        float L = Lred[row] + Lred[16 + row] + Lred[32 + row] + Lred[48 + row];
        float rinv = 1.0f / L;
        int grow = i0 + row;
        float vv[8];
#pragma unroll
        for (int k = 0; k < 8; k++) {
            float s = red[row * 132 + c0 + k] + red[(16 + row) * 132 + c0 + k] +
                      red[(32 + row) * 132 + c0 + k] + red[(48 + row) * 132 + c0 + k];
            float v = s * rinv;
            if (doElu) v = (v > 0.f) ? v : (__expf(v) - 1.0f);
            vv[k] = v;
        }
        if (writeBf) {
            ushort* orow = outb + (long)b * NN * outStride + hh * OO +
                           (long)grow * outStride + c0;
#pragma unroll
            for (int k = 0; k < 8; k++) orow[k] = f2b(vv[k]);
        } else {
            float* orow = outf + (long)b * NN * outStride + hh * OO +
                          (long)grow * outStride + c0;
            *(float4*)orow = make_float4(vv[0], vv[1], vv[2], vv[3]);
            *(float4*)(orow + 4) = make_float4(vv[4], vv[5], vv[6], vv[7]);
        }
    }
}

// ---------------- final: y = x@lin_w.T+lin_b+out2; out = relu(y@ln_w.T+ln_b)
__global__ __launch_bounds__(256) void final_mfma(
    const ushort* __restrict__ xb, const float* __restrict__ out2,
    const ushort* __restrict__ lwb, const float* __restrict__ lin_b,
    const ushort* __restrict__ nwb, const float* __restrict__ ln_b,
    float* __restrict__ out)
{
    __shared__ ushort ys[32][136];
    int t = threadIdx.x;
    int wave = t >> 6, lane = t & 63;
    int quad = lane >> 4, l16 = lane & 15;
    long row0 = (long)blockIdx.x * 32;
    int n0 = wave * 32;

    floatx4 zero = {0.f, 0.f, 0.f, 0.f};
    floatx4 acc[2][2];
#pragma unroll
    for (int mt = 0; mt < 2; mt++)
#pragma unroll
        for (int nt = 0; nt < 2; nt++) acc[mt][nt] = zero;

    for (int k0 = 0; k0 < HO; k0 += 32) {
        int kb = k0 + quad * 8;
        short8 a0 = *(const short8*)(xb + (row0 + l16) * HO + kb);
        short8 a1 = *(const short8*)(xb + (row0 + 16 + l16) * HO + kb);
        short8 b0 = *(const short8*)(lwb + (long)(n0 + l16) * HO + kb);
        short8 b1 = *(const short8*)(lwb + (long)(n0 + 16 + l16) * HO + kb);
        acc[0][0] = __builtin_amdgcn_mfma_f32_16x16x32_bf16(a0, b0, acc[0][0], 0, 0, 0);
        acc[0][1] = __builtin_amdgcn_mfma_f32_16x16x32_bf16(a0, b1, acc[0][1], 0, 0, 0);
        acc[1][0] = __builtin_amdgcn_mfma_f32_16x16x32_bf16(a1, b0, acc[1][0], 0, 0, 0);
        acc[1][1] = __builtin_amdgcn_mfma_f32_16x16x32_bf16(a1, b1, acc[1][1], 0, 0, 0);
    }

#pragma unroll
    for (int nt = 0; nt < 2; nt++) {
        int col = n0 + nt * 16 + l16;
        float lb = lin_b[col];
#pragma unroll
        for (int mt = 0; mt < 2; mt++) {
#pragma unroll
            for (int reg = 0; reg < 4; reg++) {
                int row = mt * 16 + quad * 4 + reg;
                float v = acc[mt][nt][reg] + lb + out2[(row0 + row) * OO + col];
                ys[row][col] = f2b(v);
            }
        }
    }
    __syncthreads();

    floatx4 acc2[2][2];
#pragma unroll
    for (int mt = 0; mt < 2; mt++)
#pragma unroll
        for (int nt = 0; nt < 2; nt++) acc2[mt][nt] = zero;

#pragma unroll
    for (int k0 = 0; k0 < OO; k0 += 32) {
        int kb = k0 + quad * 8;
        short8 a0 = *(const short8*)&ys[l16][kb];
        short8 a1 = *(const short8*)&ys[16 + l16][kb];
        short8 b0 = *(const short8*)(nwb + (long)(n0 + l16) * OO + kb);
        short8 b1 = *(const short8*)(nwb + (long)(n0 + 16 + l16) * OO + kb);
        acc2[0][0] = __builtin_amdgcn_mfma_f32_16x16x32_bf16(a0, b0, acc2[0][0], 0, 0, 0);
        acc2[0][1] = __builtin_amdgcn_mfma_f32_16x16x32_bf16(a0, b1, acc2[0][1], 0, 0, 0);
        acc2[1][0] = __builtin_amdgcn_mfma_f32_16x16x32_bf16(a1, b0, acc2[1][0], 0, 0, 0);
        acc2[1][1] = __builtin_amdgcn_mfma_f32_16x16x32_bf16(a1, b1, acc2[1][1], 0, 0, 0);
    }

#pragma unroll
    for (int nt = 0; nt < 2; nt++) {
        int col = n0 + nt * 16 + l16;
        float nb = ln_b[col];
#pragma unroll
        for (int mt = 0; mt < 2; mt++) {
#pragma unroll
            for (int reg = 0; reg < 4; reg++) {
                int row = mt * 16 + quad * 4 + reg;
                out[(row0 + row) * OO + col] = fmaxf(acc2[mt][nt][reg] + nb, 0.f);
            }
        }
    }
}

extern "C" void kernel_launch(void* const* d_in, const int* in_sizes, int n_in,
                              void* d_out, int out_size, void* d_ws, size_t ws_size,
                              hipStream_t stream)
{
    const float* inputs = (const float*)d_in[0];
    const int*   adj    = (const int*)d_in[1];
    const float* W_att  = (const float*)d_in[3];
    const float* a_src  = (const float*)d_in[4];
    const float* a_dst  = (const float*)d_in[5];
    const float* W_out  = (const float*)d_in[6];
    const float* ao_src = (const float*)d_in[7];
    const float* ao_dst = (const float*)d_in[8];
    const float* lin_w  = (const float*)d_in[9];
    const float* lin_b  = (const float*)d_in[10];
    const float* ln_w   = (const float*)d_in[11];
    const float* ln_b   = (const float*)d_in[12];
    float* out = (float*)d_out;

    float* ws   = (float*)d_ws;
    float* out2 = ws;
    float* s1   = ws + 1048576;
    float* s2   = ws + 1114112;
    float* s1o  = ws + 1179648;
    float* s2o  = ws + 1187840;
    ushort* ub      = (ushort*)(ws + 1196032);
    ushort* x_b     = ub;
    ushort* h_catTb = ub + 8388608;
    ushort* h2Tb    = ub + 16777216;
    ushort* W_attTb = ub + 17825792;
    ushort* W_outTb = ub + 18087936;
    ushort* lin_wb  = ub + 18219008;
    ushort* ln_wb   = ub + 18350080;
    unsigned long long* adjp = (unsigned long long*)(ub + 18366464);

    const int SH = (NN + 8448 + 64) * 4;   // 38,144 B dyn LDS

    // 0. packing / conversions
    pack_adj<<<2048, 256, 0, stream>>>(adj, adjp);
    transpose_cvt<<<dim3(4, 2, 8), 256, 0, stream>>>(W_att, W_attTb, FF, OO);
    transpose_cvt<<<dim3(16, 2, 1), 256, 0, stream>>>(W_out, W_outTb, HO, OO);
    cvt_bf16_2<<<72, 256, 0, stream>>>(lin_w, lin_wb, 131072L, ln_w, ln_wb);
    // 1. h^T (packed) = (inputs @ W_att)^T per (b,h), bf16; fused s1/s2
    gemmT<<<dim3(16, 64), 256, 0, stream>>>(
        W_attTb, inputs, h_catTb, s1, s2, a_src, a_dst, FF, HH);
    // 2. layer-0 attention -> x = elu(att@h) bf16
    attn_mfma<2><<<dim3(16, 64), 256, SH, stream>>>(
        s1, s2, h_catTb, (const uint*)adjp, (float*)nullptr, x_b, HH, HO, 1, 1);
    // 3. h2^T (packed) = (x @ W_out)^T per b, split-K x4; fused s1o/s2o
    gemmT_sk<<<dim3(64, 8), 256, 0, stream>>>(
        W_outTb, x_b, h2Tb, s1o, s2o, ao_src, ao_dst);
    // 4. layer-1 attention -> out2 fp32 (no elu), j-split x4
    attn_mfma<4><<<dim3(64, 8), 256, SH, stream>>>(
        s1o, s2o, h2Tb, (const uint*)adjp, out2, (ushort*)nullptr, 1, OO, 0, 0);
    // 5. out = relu((x@lin_w.T + lin_b + out2) @ ln_w.T + ln_b)
    final_mfma<<<256, 256, 0, stream>>>(
        x_b, out2, lin_wb, lin_b, ln_wb, ln_b, out);
}

// Round 11
// 214.520 us; speedup vs baseline: 1.1642x; 1.1642x over previous
//
#include <hip/hip_runtime.h>

// GAT forward, MI355X. Round 10: fragment-pack ALL GEMM operands (R4's h^T
// trick): pack_weights pre-kernel (W_att/W_out/lin_w/ln_w -> packed bf16),
// gemmT0 stages B in LDS (packed, pad 520) + contiguous packed A-loads;
// gemmT_sk/final_mfma read packed weights. attn kernels byte-identical to R9.
// B=8, N=1024, F=256, O=128, H=8, HO=1024, BH=64.
//
// packed layout (K x C operand, fragment for lane16=c, quad*8=k):
//   elem (k,c) at (k>>3)*(C*8) + c*8 + (k&7)   -> 256 B contiguous per quad.
//
// ws floats:
//   out2 [8192,128] @ 0        (1,048,576)
//   s1 @ 1048576  s2 @ 1114112 (65,536 each)
//   s1o @ 1179648 s2o @ 1187840 (8,192 each)
// ushort region @ float offset 1196032:
//   x_b     [8,1024,1024] @ 0         h_catTb @ 8388608   h2Tb @ 16777216
//   WAp @ 17825792 (262144)   WOp @ 18087936 (131072)
//   LWp @ 18219008 (131072)   NWp @ 18350080 (16384)
//   adjp (ull[8192*16]) @ ushort 18366464  (1 MB)

#define NN 1024
#define FF 256
#define OO 128
#define HH 8
#define HO 1024

typedef __attribute__((ext_vector_type(8))) short short8;
typedef __attribute__((ext_vector_type(4))) float floatx4;

__device__ __forceinline__ ushort f2b(float f) {
    union { float f; unsigned u; } v; v.f = f;
    unsigned r = v.u + 0x7FFFu + ((v.u >> 16) & 1u);   // RNE
    return (ushort)(r >> 16);
}

// ---------------- adj int32 -> bitmask (standalone; 8192 waves, BW-bound) ---
__global__ __launch_bounds__(256) void pack_adj(
    const int* __restrict__ adj, unsigned long long* __restrict__ adjp)
{
    int w = blockIdx.x * 4 + (threadIdx.x >> 6);   // row 0..8191 (= b*N+i)
    int lane = threadIdx.x & 63;
    const int* row = adj + (long)w * NN;
#pragma unroll
    for (int it = 0; it < 16; it++) {
        unsigned long long m = __ballot(row[it * 64 + lane] > 0);
        if (lane == 0) adjp[(long)w * 16 + it] = m;
    }
}

// ---------------- all weights -> fragment-packed bf16 (one launch) ----------
// seg0 W_att [8][256][128] k-major -> WAp[h][(k>>3)*1024 + o*8 + (k&7)]
// seg1 W_out [1024][128]   k-major -> WOp[(k>>3)*1024 + o*8 + (k&7)]
// seg2 lin_w [128][1024]   c-major -> LWp[(k>>3)*1024 + c*8 + (k&7)]
// seg3 ln_w  [128][128]    c-major -> NWp[(k>>3)*1024 + c*8 + (k&7)]
// grid 264 x 256 = 67,584 threads exactly.
__global__ __launch_bounds__(256) void pack_weights(
    const float* __restrict__ W_att, const float* __restrict__ W_out,
    const float* __restrict__ lin_w, const float* __restrict__ ln_w,
    ushort* __restrict__ WAp, ushort* __restrict__ WOp,
    ushort* __restrict__ LWp, ushort* __restrict__ NWp)
{
    int tid = blockIdx.x * 256 + threadIdx.x;
    float v[8];
    ushort* dst;
    if (tid < 32768) {                       // W_att
        int h = tid >> 12, rem = tid & 4095, kc = rem >> 7, o = rem & 127;
        const float* s = W_att + h * 32768;
#pragma unroll
        for (int i = 0; i < 8; i++) v[i] = s[(kc * 8 + i) * 128 + o];
        dst = WAp + h * 32768 + kc * 1024 + o * 8;
    } else if (tid < 49152) {                // W_out
        int t2 = tid - 32768;
        int kc = t2 >> 7, o = t2 & 127;
#pragma unroll
        for (int i = 0; i < 8; i++) v[i] = W_out[(kc * 8 + i) * 128 + o];
        dst = WOp + kc * 1024 + o * 8;
    } else if (tid < 65536) {                // lin_w
        int t3 = tid - 49152;
        int kc = t3 >> 7, c = t3 & 127;
        float4 a = *(const float4*)(lin_w + c * 1024 + kc * 8);
        float4 bq = *(const float4*)(lin_w + c * 1024 + kc * 8 + 4);
        v[0] = a.x; v[1] = a.y; v[2] = a.z; v[3] = a.w;
        v[4] = bq.x; v[5] = bq.y; v[6] = bq.z; v[7] = bq.w;
        dst = LWp + kc * 1024 + c * 8;
    } else {                                 // ln_w
        int t4 = tid - 65536;
        int kc = t4 >> 7, c = t4 & 127;
        float4 a = *(const float4*)(ln_w + c * 128 + kc * 8);
        float4 bq = *(const float4*)(ln_w + c * 128 + kc * 8 + 4);
        v[0] = a.x; v[1] = a.y; v[2] = a.z; v[3] = a.w;
        v[4] = bq.x; v[5] = bq.y; v[6] = bq.z; v[7] = bq.w;
        dst = NWp + kc * 1024 + c * 8;
    }
    union { ushort s[8]; uint4 q; } u;
#pragma unroll
    for (int i = 0; i < 8; i++) u.s[i] = f2b(v[i]);
    *(uint4*)dst = u.q;
}

// ---------------- layer-0 GEMM: packed-A weights + LDS-staged packed B ------
// h^T[o][n] = sum_k W[o][k]*inputs[n][k] per (b,hh); fused s1/s2 dots;
// packed h^T store. Block = 64 n-cols, 4 waves (16 n each, full o=128).
__global__ __launch_bounds__(256) void gemmT0(
    const ushort* __restrict__ WAp, const float* __restrict__ inputs,
    ushort* __restrict__ Cb, float* __restrict__ s1, float* __restrict__ s2,
    const float* __restrict__ a1g, const float* __restrict__ a2g)
{
    __shared__ ushort Bs[32 * 520];   // [kc][64 rows][8], kc-stride 520 (pad) = 33,280 B
    int t = threadIdx.x;
    int wave = t >> 6, lane = t & 63;
    int quad = lane >> 4, l16 = lane & 15;
    int bh = blockIdx.y;
    int hh = bh & 7, b = bh >> 3;
    int nblk = blockIdx.x * 64;
    int n0w = nblk + wave * 16;

    // stage B (64 rows x K=256 fp32 -> bf16 packed): coalesced 1KB/wave reads
    const float* binp = inputs + ((long)b * NN + nblk) * FF;
#pragma unroll
    for (int it = 0; it < 8; it++) {
        int pid = it * 256 + t;
        int kc = pid & 31, r = pid >> 5;
        float4 va = *(const float4*)(binp + r * FF + kc * 8);
        float4 vb = *(const float4*)(binp + r * FF + kc * 8 + 4);
        union { ushort s[8]; uint4 q; } u;
        u.s[0] = f2b(va.x); u.s[1] = f2b(va.y); u.s[2] = f2b(va.z); u.s[3] = f2b(va.w);
        u.s[4] = f2b(vb.x); u.s[5] = f2b(vb.y); u.s[6] = f2b(vb.z); u.s[7] = f2b(vb.w);
        *(uint4*)&Bs[kc * 520 + r * 8] = u.q;
    }
    __syncthreads();

    const ushort* A = WAp + hh * 32768;
    int nl = wave * 16 + l16;
    floatx4 acc[8];
    floatx4 zero = {0.f, 0.f, 0.f, 0.f};
#pragma unroll
    for (int mt = 0; mt < 8; mt++) acc[mt] = zero;

#pragma unroll 2
    for (int kc2 = 0; kc2 < 8; kc2++) {
        int kc = kc2 * 4 + quad;
        short8 bfr = *(const short8*)&Bs[kc * 520 + nl * 8];
#pragma unroll
        for (int mt = 0; mt < 8; mt++) {
            short8 af = *(const short8*)(A + kc * 1024 + (mt * 16 + l16) * 8);
            acc[mt] = __builtin_amdgcn_mfma_f32_16x16x32_bf16(af, bfr, acc[mt], 0, 0, 0);
        }
    }

    const float* a1 = a1g + hh * OO;
    const float* a2 = a2g + hh * OO;
    float sp1 = 0.f, sp2 = 0.f;
#pragma unroll
    for (int mt = 0; mt < 8; mt++) {
        float4 v1 = *(const float4*)(a1 + mt * 16 + quad * 4);
        float4 v2 = *(const float4*)(a2 + mt * 16 + quad * 4);
        sp1 += acc[mt][0] * v1.x + acc[mt][1] * v1.y + acc[mt][2] * v1.z + acc[mt][3] * v1.w;
        sp2 += acc[mt][0] * v2.x + acc[mt][1] * v2.y + acc[mt][2] * v2.z + acc[mt][3] * v2.w;
    }
    sp1 += __shfl_xor(sp1, 16); sp1 += __shfl_xor(sp1, 32);
    sp2 += __shfl_xor(sp2, 16); sp2 += __shfl_xor(sp2, 32);
    if (lane < 16) {
        s1[(long)bh * NN + n0w + l16] = sp1;
        s2[(long)bh * NN + n0w + l16] = sp2;
    }

    // store h^T bf16, fragment-packed: (o,n) -> (n>>3)*1024 + o*8 + (n&7)
    ushort* cb = Cb + (long)bh * OO * NN;
    int n = n0w + l16;
    int base = (n >> 3) * 1024 + (n & 7);
#pragma unroll
    for (int mt = 0; mt < 8; mt++) {
#pragma unroll
        for (int reg = 0; reg < 4; reg++) {
            int o = mt * 16 + quad * 4 + reg;
            cb[base + o * 8] = f2b(acc[mt][reg]);
        }
    }
}

// ---------------- layer-1: split-K bf16 MFMA GEMM + LDS reduce + fused dots -
// A = WOp (fragment-packed) -> contiguous 256B/quad loads.
__global__ __launch_bounds__(256) void gemmT_sk(
    const ushort* __restrict__ WOp,   // packed [kc][o][8]
    const ushort* __restrict__ Bb,    // x_b [8192][1024] row-major
    ushort* __restrict__ Cb,          // h2^T packed per b
    float* __restrict__ s1, float* __restrict__ s2,
    const float* __restrict__ a1g, const float* __restrict__ a2g)
{
    __shared__ float red[4 * 2304];   // [wave][o*18 + nl], 36,864 B
    int t = threadIdx.x;
    int wave = t >> 6, lane = t & 63;
    int quad = lane >> 4, l16 = lane & 15;
    int b = blockIdx.y;
    int n0 = blockIdx.x * 16;

    const ushort* brow = Bb + ((long)b * NN + n0 + l16) * HO;
    int kbase = wave * 256;

    floatx4 acc[8];
    floatx4 zero = {0.f, 0.f, 0.f, 0.f};
#pragma unroll
    for (int mt = 0; mt < 8; mt++) acc[mt] = zero;

    for (int k0 = 0; k0 < 256; k0 += 32) {
        int kb = kbase + k0 + quad * 8;
        int kch = kb >> 3;
        short8 bfr = *(const short8*)(brow + kb);
#pragma unroll
        for (int mt = 0; mt < 8; mt++) {
            short8 af = *(const short8*)(WOp + kch * 1024 + (mt * 16 + l16) * 8);
            acc[mt] = __builtin_amdgcn_mfma_f32_16x16x32_bf16(af, bfr, acc[mt], 0, 0, 0);
        }
    }

#pragma unroll
    for (int mt = 0; mt < 8; mt++)
#pragma unroll
        for (int reg = 0; reg < 4; reg++)
            red[wave * 2304 + (mt * 16 + quad * 4 + reg) * 18 + l16] = acc[mt][reg];
    __syncthreads();

    int nl = t & 15, g = t >> 4, o0 = g * 8;
    float s[8];
#pragma unroll
    for (int k = 0; k < 8; k++) {
        int idx = (o0 + k) * 18 + nl;
        s[k] = red[idx] + red[2304 + idx] + red[4608 + idx] + red[6912 + idx];
    }

    float p1 = 0.f, p2 = 0.f;
#pragma unroll
    for (int k = 0; k < 8; k++) {
        p1 += s[k] * a1g[o0 + k];
        p2 += s[k] * a2g[o0 + k];
    }

    ushort* cb = Cb + (long)b * OO * NN;
    int nglob = n0 + nl;
    int base = (nglob >> 3) * 1024 + (nglob & 7);
#pragma unroll
    for (int k = 0; k < 8; k++) cb[base + (o0 + k) * 8] = f2b(s[k]);

    __syncthreads();
    red[g * 16 + nl] = p1;
    red[256 + g * 16 + nl] = p2;
    __syncthreads();
    if (t < 16) {
        float q1 = 0.f, q2 = 0.f;
#pragma unroll
        for (int gg = 0; gg < 16; gg++) {
            q1 += red[gg * 16 + t];
            q2 += red[256 + gg * 16 + t];
        }
        s1[(long)b * NN + n0 + t] = q1;
        s2[(long)b * NN + n0 + t] = q2;
    }
}

// ---------------- single-pass masked-softmax attention + MFMA PV ------------
// BYTE-IDENTICAL to R9 (twice-passing R5 inner loop).
// dyn LDS: s2s[1024] | red[8448] (stride 132) | Lred[64]  = 38,144 B
template <int JS>
__global__ __launch_bounds__(256) void attn_mfma(
    const float* __restrict__ s1g, const float* __restrict__ s2g,
    const ushort* __restrict__ hTp, const uint* __restrict__ adjp,
    float* __restrict__ outf, ushort* __restrict__ outb,
    int Hh, int outStride, int doElu, int writeBf)
{
    extern __shared__ float smem_f[];
    float* s2s = smem_f;
    float* red = smem_f + NN;
    float* Lred = red + 8448;

    int t = threadIdx.x;
    int wave = t >> 6, lane = t & 63;
    int quad = lane >> 4, l16 = lane & 15;
    int bh = blockIdx.y;
    int hh = bh % Hh, b = bh / Hh;

    const float* s2r = s2g + (long)bh * NN;
    for (int j = t; j < NN; j += 256) s2s[j] = s2r[j];
    __syncthreads();

    const ushort* hT = hTp + (long)bh * OO * NN;
    const ushort* hbase = hT + quad * 1024 + l16 * 8;
    floatx4 zero = {0.f, 0.f, 0.f, 0.f};

    if (JS == 2) {
        int ig = wave >> 1, jh = wave & 1;
        int i0 = blockIdx.x * 64 + ig * 32;
        int j_lo = jh * (NN / 2), j_hi = j_lo + NN / 2;

        float s1a = s1g[(long)bh * NN + i0 + l16];
        float s1b = s1g[(long)bh * NN + i0 + 16 + l16];
        const uint* abA = adjp + ((long)b * NN + i0 + l16) * 32;
        const uint* abB = abA + 16 * 32;

        floatx4 acc0[8], acc1[8];
#pragma unroll
        for (int ot = 0; ot < 8; ot++) { acc0[ot] = zero; acc1[ot] = zero; }
        float Lp0 = 0.f, Lp1 = 0.f;

        for (int j0 = j_lo; j0 < j_hi; j0 += 32) {
            const ushort* hp = hbase + (j0 >> 3) * 1024;
            short8 bf[8];
#pragma unroll
            for (int ot = 0; ot < 8; ot++)
                bf[ot] = *(const short8*)(hp + ot * 128);
            uint mbA = (abA[j0 >> 5] >> (quad * 8)) & 0xffu;
            uint mbB = (abB[j0 >> 5] >> (quad * 8)) & 0xffu;
            int kb = j0 + quad * 8;
            float4 sA4 = *(const float4*)(s2s + kb);
            float4 sB4 = *(const float4*)(s2s + kb + 4);
            float se[8] = {sA4.x, sA4.y, sA4.z, sA4.w, sB4.x, sB4.y, sB4.z, sB4.w};
            short8 afA, afB;
#pragma unroll
            for (int e = 0; e < 8; e++) {
                float ea = s1a + se[e]; ea = fmaxf(ea, 0.2f * ea);
                float eb = s1b + se[e]; eb = fmaxf(eb, 0.2f * eb);
                union { float f; uint u; } wa, wb;
                wa.f = ((mbA >> e) & 1u) ? __expf(ea) : 0.f;
                wb.f = ((mbB >> e) & 1u) ? __expf(eb) : 0.f;
                wa.u &= 0xffff0000u; wb.u &= 0xffff0000u;   // truncate to bf16
                afA[e] = (short)(wa.u >> 16);
                afB[e] = (short)(wb.u >> 16);
                Lp0 += wa.f; Lp1 += wb.f;
            }
#pragma unroll
            for (int ot = 0; ot < 8; ot++) {
                acc0[ot] = __builtin_amdgcn_mfma_f32_16x16x32_bf16(afA, bf[ot], acc0[ot], 0, 0, 0);
                acc1[ot] = __builtin_amdgcn_mfma_f32_16x16x32_bf16(afB, bf[ot], acc1[ot], 0, 0, 0);
            }
        }

        Lp0 += __shfl_xor(Lp0, 16); Lp0 += __shfl_xor(Lp0, 32);
        Lp1 += __shfl_xor(Lp1, 16); Lp1 += __shfl_xor(Lp1, 32);

        if (jh == 1) {
#pragma unroll
            for (int ot = 0; ot < 8; ot++)
#pragma unroll
                for (int reg = 0; reg < 4; reg++) {
                    red[(ig * 32 + quad * 4 + reg) * 132 + ot * 16 + l16] = acc0[ot][reg];
                    red[(ig * 32 + 16 + quad * 4 + reg) * 132 + ot * 16 + l16] = acc1[ot][reg];
                }
            if (lane < 16) {
                Lred[(ig * 2 + 0) * 16 + l16] = Lp0;
                Lred[(ig * 2 + 1) * 16 + l16] = Lp1;
            }
        }
        __syncthreads();
        if (jh == 0) {
            float r0 = 1.0f / (Lp0 + Lred[(ig * 2 + 0) * 16 + l16]);
            float r1 = 1.0f / (Lp1 + Lred[(ig * 2 + 1) * 16 + l16]);
#pragma unroll
            for (int tile = 0; tile < 2; tile++) {
                float rv = tile ? r1 : r0;
                floatx4* ac = tile ? acc1 : acc0;
#pragma unroll
                for (int reg = 0; reg < 4; reg++) {
                    float linv = __shfl(rv, quad * 4 + reg);
                    int rloc = ig * 32 + tile * 16 + quad * 4 + reg;
                    int row = blockIdx.x * 64 + rloc;
                    if (writeBf) {
                        ushort* orow = outb + (long)b * NN * outStride + hh * OO +
                                       (long)row * outStride + l16;
#pragma unroll
                        for (int ot = 0; ot < 8; ot++) {
                            float v = (ac[ot][reg] + red[rloc * 132 + ot * 16 + l16]) * linv;
                            if (doElu) v = (v > 0.f) ? v : (__expf(v) - 1.0f);
                            orow[ot * 16] = f2b(v);
                        }
                    } else {
                        float* orow = outf + (long)b * NN * outStride + hh * OO +
                                      (long)row * outStride + l16;
#pragma unroll
                        for (int ot = 0; ot < 8; ot++) {
                            float v = (ac[ot][reg] + red[rloc * 132 + ot * 16 + l16]) * linv;
                            if (doElu) v = (v > 0.f) ? v : (__expf(v) - 1.0f);
                            orow[ot * 16] = v;
                        }
                    }
                }
            }
        }
    } else {   // JS == 4
        int i0 = blockIdx.x * 16;
        int j_lo = wave * (NN / 4), j_hi = j_lo + NN / 4;

        float s1a = s1g[(long)bh * NN + i0 + l16];
        const uint* abA = adjp + ((long)b * NN + i0 + l16) * 32;

        floatx4 acc[8];
#pragma unroll
        for (int ot = 0; ot < 8; ot++) acc[ot] = zero;
        float Lp = 0.f;

        for (int j0 = j_lo; j0 < j_hi; j0 += 32) {
            const ushort* hp = hbase + (j0 >> 3) * 1024;
            short8 bf[8];
#pragma unroll
            for (int ot = 0; ot < 8; ot++)
                bf[ot] = *(const short8*)(hp + ot * 128);
            uint mbA = (abA[j0 >> 5] >> (quad * 8)) & 0xffu;
            int kb = j0 + quad * 8;
            float4 sA4 = *(const float4*)(s2s + kb);
            float4 sB4 = *(const float4*)(s2s + kb + 4);
            float se[8] = {sA4.x, sA4.y, sA4.z, sA4.w, sB4.x, sB4.y, sB4.z, sB4.w};
            short8 afA;
#pragma unroll
            for (int e = 0; e < 8; e++) {
                float ea = s1a + se[e]; ea = fmaxf(ea, 0.2f * ea);
                union { float f; uint u; } wa;
                wa.f = ((mbA >> e) & 1u) ? __expf(ea) : 0.f;
                wa.u &= 0xffff0000u;
                afA[e] = (short)(wa.u >> 16);
                Lp += wa.f;
            }
#pragma unroll
            for (int ot = 0; ot < 8; ot++)
                acc[ot] = __builtin_amdgcn_mfma_f32_16x16x32_bf16(afA, bf[ot], acc[ot], 0, 0, 0);
        }

        Lp += __shfl_xor(Lp, 16); Lp += __shfl_xor(Lp, 32);
#pragma unroll
        for (int ot = 0; ot < 8; ot++)
#pragma unroll
            for (int reg = 0; reg < 4; reg++)
                red[(wave * 16 + quad * 4 + reg) * 132 + ot * 16 + l16] = acc[ot][reg];
        if (lane < 16) Lred[wave * 16 + l16] = Lp;
        __syncthreads();
        int row = t >> 4, c0 = (t & 15) * 8;
        float L = Lred[row] + Lred[16 + row] + Lred[32 + row] + Lred[48 + row];
        float rinv = 1.0f / L;
        int grow = i0 + row;
        float vv[8];
#pragma unroll
        for (int k = 0; k < 8; k++) {
            float s = red[row * 132 + c0 + k] + red[(16 + row) * 132 + c0 + k] +
                      red[(32 + row) * 132 + c0 + k] + red[(48 + row) * 132 + c0 + k];
            float v = s * rinv;
            if (doElu) v = (v > 0.f) ? v : (__expf(v) - 1.0f);
            vv[k] = v;
        }
        if (writeBf) {
            ushort* orow = outb + (long)b * NN * outStride + hh * OO +
                           (long)grow * outStride + c0;
#pragma unroll
            for (int k = 0; k < 8; k++) orow[k] = f2b(vv[k]);
        } else {
            float* orow = outf + (long)b * NN * outStride + hh * OO +
                          (long)grow * outStride + c0;
            *(float4*)orow = make_float4(vv[0], vv[1], vv[2], vv[3]);
            *(float4*)(orow + 4) = make_float4(vv[4], vv[5], vv[6], vv[7]);
        }
    }
}

// ---------------- final: y = x@lin_w.T+lin_b+out2; out = relu(y@ln_w.T+ln_b)
// B-operands from packed LWp/NWp (contiguous 256B/quad loads).
__global__ __launch_bounds__(256) void final_mfma(
    const ushort* __restrict__ xb, const float* __restrict__ out2,
    const ushort* __restrict__ LWp, const float* __restrict__ lin_b,
    const ushort* __restrict__ NWp, const float* __restrict__ ln_b,
    float* __restrict__ out)
{
    __shared__ ushort ys[32][136];
    int t = threadIdx.x;
    int wave = t >> 6, lane = t & 63;
    int quad = lane >> 4, l16 = lane & 15;
    long row0 = (long)blockIdx.x * 32;
    int n0 = wave * 32;

    floatx4 zero = {0.f, 0.f, 0.f, 0.f};
    floatx4 acc[2][2];
#pragma unroll
    for (int mt = 0; mt < 2; mt++)
#pragma unroll
        for (int nt = 0; nt < 2; nt++) acc[mt][nt] = zero;

    for (int k0 = 0; k0 < HO; k0 += 32) {
        int kb = k0 + quad * 8;
        int kch = kb >> 3;
        short8 a0 = *(const short8*)(xb + (row0 + l16) * HO + kb);
        short8 a1 = *(const short8*)(xb + (row0 + 16 + l16) * HO + kb);
        short8 b0 = *(const short8*)(LWp + kch * 1024 + (n0 + l16) * 8);
        short8 b1 = *(const short8*)(LWp + kch * 1024 + (n0 + 16 + l16) * 8);
        acc[0][0] = __builtin_amdgcn_mfma_f32_16x16x32_bf16(a0, b0, acc[0][0], 0, 0, 0);
        acc[0][1] = __builtin_amdgcn_mfma_f32_16x16x32_bf16(a0, b1, acc[0][1], 0, 0, 0);
        acc[1][0] = __builtin_amdgcn_mfma_f32_16x16x32_bf16(a1, b0, acc[1][0], 0, 0, 0);
        acc[1][1] = __builtin_amdgcn_mfma_f32_16x16x32_bf16(a1, b1, acc[1][1], 0, 0, 0);
    }

#pragma unroll
    for (int nt = 0; nt < 2; nt++) {
        int col = n0 + nt * 16 + l16;
        float lb = lin_b[col];
#pragma unroll
        for (int mt = 0; mt < 2; mt++) {
#pragma unroll
            for (int reg = 0; reg < 4; reg++) {
                int row = mt * 16 + quad * 4 + reg;
                float v = acc[mt][nt][reg] + lb + out2[(row0 + row) * OO + col];
                ys[row][col] = f2b(v);
            }
        }
    }
    __syncthreads();

    floatx4 acc2[2][2];
#pragma unroll
    for (int mt = 0; mt < 2; mt++)
#pragma unroll
        for (int nt = 0; nt < 2; nt++) acc2[mt][nt] = zero;

#pragma unroll
    for (int k0 = 0; k0 < OO; k0 += 32) {
        int kb = k0 + quad * 8;
        int kch = kb >> 3;
        short8 a0 = *(const short8*)&ys[l16][kb];
        short8 a1 = *(const short8*)&ys[16 + l16][kb];
        short8 b0 = *(const short8*)(NWp + kch * 1024 + (n0 + l16) * 8);
        short8 b1 = *(const short8*)(NWp + kch * 1024 + (n0 + 16 + l16) * 8);
        acc2[0][0] = __builtin_amdgcn_mfma_f32_16x16x32_bf16(a0, b0, acc2[0][0], 0, 0, 0);
        acc2[0][1] = __builtin_amdgcn_mfma_f32_16x16x32_bf16(a0, b1, acc2[0][1], 0, 0, 0);
        acc2[1][0] = __builtin_amdgcn_mfma_f32_16x16x32_bf16(a1, b0, acc2[1][0], 0, 0, 0);
        acc2[1][1] = __builtin_amdgcn_mfma_f32_16x16x32_bf16(a1, b1, acc2[1][1], 0, 0, 0);
    }

#pragma unroll
    for (int nt = 0; nt < 2; nt++) {
        int col = n0 + nt * 16 + l16;
        float nb = ln_b[col];
#pragma unroll
        for (int mt = 0; mt < 2; mt++) {
#pragma unroll
            for (int reg = 0; reg < 4; reg++) {
                int row = mt * 16 + quad * 4 + reg;
                out[(row0 + row) * OO + col] = fmaxf(acc2[mt][nt][reg] + nb, 0.f);
            }
        }
    }
}

extern "C" void kernel_launch(void* const* d_in, const int* in_sizes, int n_in,
                              void* d_out, int out_size, void* d_ws, size_t ws_size,
                              hipStream_t stream)
{
    const float* inputs = (const float*)d_in[0];
    const int*   adj    = (const int*)d_in[1];
    const float* W_att  = (const float*)d_in[3];
    const float* a_src  = (const float*)d_in[4];
    const float* a_dst  = (const float*)d_in[5];
    const float* W_out  = (const float*)d_in[6];
    const float* ao_src = (const float*)d_in[7];
    const float* ao_dst = (const float*)d_in[8];
    const float* lin_w  = (const float*)d_in[9];
    const float* lin_b  = (const float*)d_in[10];
    const float* ln_w   = (const float*)d_in[11];
    const float* ln_b   = (const float*)d_in[12];
    float* out = (float*)d_out;

    float* ws   = (float*)d_ws;
    float* out2 = ws;
    float* s1   = ws + 1048576;
    float* s2   = ws + 1114112;
    float* s1o  = ws + 1179648;
    float* s2o  = ws + 1187840;
    ushort* ub      = (ushort*)(ws + 1196032);
    ushort* x_b     = ub;
    ushort* h_catTb = ub + 8388608;
    ushort* h2Tb    = ub + 16777216;
    ushort* WAp     = ub + 17825792;
    ushort* WOp     = ub + 18087936;
    ushort* LWp     = ub + 18219008;
    ushort* NWp     = ub + 18350080;
    unsigned long long* adjp = (unsigned long long*)(ub + 18366464);

    const int SH = (NN + 8448 + 64) * 4;   // 38,144 B dyn LDS (attn)

    // 0. packing (2 launches)
    pack_adj<<<2048, 256, 0, stream>>>(adj, adjp);
    pack_weights<<<264, 256, 0, stream>>>(
        W_att, W_out, lin_w, ln_w, WAp, WOp, LWp, NWp);
    // 1. h^T (packed) = (inputs @ W_att)^T per (b,h), bf16; fused s1/s2
    gemmT0<<<dim3(16, 64), 256, 0, stream>>>(
        WAp, inputs, h_catTb, s1, s2, a_src, a_dst);
    // 2. layer-0 attention -> x = elu(att@h) bf16
    attn_mfma<2><<<dim3(16, 64), 256, SH, stream>>>(
        s1, s2, h_catTb, (const uint*)adjp, (float*)nullptr, x_b, HH, HO, 1, 1);
    // 3. h2^T (packed) = (x @ W_out)^T per b, split-K x4; fused s1o/s2o
    gemmT_sk<<<dim3(64, 8), 256, 0, stream>>>(
        WOp, x_b, h2Tb, s1o, s2o, ao_src, ao_dst);
    // 4. layer-1 attention -> out2 fp32 (no elu), j-split x4
    attn_mfma<4><<<dim3(64, 8), 256, SH, stream>>>(
        s1o, s2o, h2Tb, (const uint*)adjp, out2, (ushort*)nullptr, 1, OO, 0, 0);
    // 5. out = relu((x@lin_w.T + lin_b + out2) @ ln_w.T + ln_b)
    final_mfma<<<256, 256, 0, stream>>>(
        x_b, out2, LWp, lin_b, NWp, ln_b, out);
}

// Round 12
// 208.683 us; speedup vs baseline: 1.1968x; 1.0280x over previous
//
#include <hip/hip_runtime.h>

// GAT forward, MI355X. Round 11:
//  (1) attn L computed by MFMA vs const-ones B-fragment (kills Lp adds,
//      truncation ANDs, and all epilogue shuffles; A-frags bit-identical),
//  (2) x_b fragment-packed (attn0 write / gemmT_sk B / final A all 256B-
//      contiguous per quad),
//  (3) pack_adj+pack_weights merged (6 launches).
// B=8, N=1024, F=256, O=128, H=8, HO=1024, BH=64.
//
// packed layout (R rows x K cols): elem (r,k) at (k>>3)*(R*8) + r*8 + (k&7).
// x_b packed: R=8192 rows (b*N+n), K=1024 -> chunk stride 65536.
// h^T packed per (b,h): R=128 o-rows as cols... elem (j,o) at
//   (j>>3)*1024 + o*8 + (j&7)  (j-chunks, unchanged from R4).
//
// ws floats:
//   out2 [8192,128] @ 0        (1,048,576)
//   s1 @ 1048576  s2 @ 1114112 (65,536 each)
//   s1o @ 1179648 s2o @ 1187840 (8,192 each)
// ushort region @ float offset 1196032:
//   x_b(packed) @ 0        h_catTb @ 8388608   h2Tb @ 16777216
//   WAp @ 17825792 (262144)   WOp @ 18087936 (131072)
//   LWp @ 18219008 (131072)   NWp @ 18350080 (16384)
//   adjp (ull[8192*16]) @ ushort 18366464  (1 MB)

#define NN 1024
#define FF 256
#define OO 128
#define HH 8
#define HO 1024

typedef __attribute__((ext_vector_type(8))) short short8;
typedef __attribute__((ext_vector_type(4))) float floatx4;

__device__ __forceinline__ ushort f2b(float f) {
    union { float f; unsigned u; } v; v.f = f;
    unsigned r = v.u + 0x7FFFu + ((v.u >> 16) & 1u);   // RNE
    return (ushort)(r >> 16);
}

// ---------------- merged packing: adj bitmask + all weights -----------------
// blocks [0,2048): adj rows (4 rows/block, ballot). blocks [2048,2312):
// weights -> fragment-packed bf16 (67,584 weight-threads exactly).
__global__ __launch_bounds__(256) void pack_all(
    const int* __restrict__ adj, unsigned long long* __restrict__ adjp,
    const float* __restrict__ W_att, const float* __restrict__ W_out,
    const float* __restrict__ lin_w, const float* __restrict__ ln_w,
    ushort* __restrict__ WAp, ushort* __restrict__ WOp,
    ushort* __restrict__ LWp, ushort* __restrict__ NWp)
{
    if (blockIdx.x < 2048) {
        int w = blockIdx.x * 4 + (threadIdx.x >> 6);
        int lane = threadIdx.x & 63;
        const int* row = adj + (long)w * NN;
#pragma unroll
        for (int it = 0; it < 16; it++) {
            unsigned long long m = __ballot(row[it * 64 + lane] > 0);
            if (lane == 0) adjp[(long)w * 16 + it] = m;
        }
        return;
    }
    int tid = (blockIdx.x - 2048) * 256 + threadIdx.x;
    float v[8];
    ushort* dst;
    if (tid < 32768) {                       // W_att [8][256][128]
        int h = tid >> 12, rem = tid & 4095, kc = rem >> 7, o = rem & 127;
        const float* s = W_att + h * 32768;
#pragma unroll
        for (int i = 0; i < 8; i++) v[i] = s[(kc * 8 + i) * 128 + o];
        dst = WAp + h * 32768 + kc * 1024 + o * 8;
    } else if (tid < 49152) {                // W_out [1024][128]
        int t2 = tid - 32768;
        int kc = t2 >> 7, o = t2 & 127;
#pragma unroll
        for (int i = 0; i < 8; i++) v[i] = W_out[(kc * 8 + i) * 128 + o];
        dst = WOp + kc * 1024 + o * 8;
    } else if (tid < 65536) {                // lin_w [128][1024]
        int t3 = tid - 49152;
        int kc = t3 >> 7, c = t3 & 127;
        float4 a = *(const float4*)(lin_w + c * 1024 + kc * 8);
        float4 bq = *(const float4*)(lin_w + c * 1024 + kc * 8 + 4);
        v[0] = a.x; v[1] = a.y; v[2] = a.z; v[3] = a.w;
        v[4] = bq.x; v[5] = bq.y; v[6] = bq.z; v[7] = bq.w;
        dst = LWp + kc * 1024 + c * 8;
    } else {                                 // ln_w [128][128]
        int t4 = tid - 65536;
        int kc = t4 >> 7, c = t4 & 127;
        float4 a = *(const float4*)(ln_w + c * 128 + kc * 8);
        float4 bq = *(const float4*)(ln_w + c * 128 + kc * 8 + 4);
        v[0] = a.x; v[1] = a.y; v[2] = a.z; v[3] = a.w;
        v[4] = bq.x; v[5] = bq.y; v[6] = bq.z; v[7] = bq.w;
        dst = NWp + kc * 1024 + c * 8;
    }
    union { ushort s[8]; uint4 q; } u;
#pragma unroll
    for (int i = 0; i < 8; i++) u.s[i] = f2b(v[i]);
    *(uint4*)dst = u.q;
}

// ---------------- layer-0 GEMM: packed-A weights + LDS-staged packed B ------
__global__ __launch_bounds__(256) void gemmT0(
    const ushort* __restrict__ WAp, const float* __restrict__ inputs,
    ushort* __restrict__ Cb, float* __restrict__ s1, float* __restrict__ s2,
    const float* __restrict__ a1g, const float* __restrict__ a2g)
{
    __shared__ ushort Bs[32 * 520];   // [kc][64 rows][8], 33,280 B
    int t = threadIdx.x;
    int wave = t >> 6, lane = t & 63;
    int quad = lane >> 4, l16 = lane & 15;
    int bh = blockIdx.y;
    int hh = bh & 7, b = bh >> 3;
    int nblk = blockIdx.x * 64;
    int n0w = nblk + wave * 16;

    const float* binp = inputs + ((long)b * NN + nblk) * FF;
#pragma unroll
    for (int it = 0; it < 8; it++) {
        int pid = it * 256 + t;
        int kc = pid & 31, r = pid >> 5;
        float4 va = *(const float4*)(binp + r * FF + kc * 8);
        float4 vb = *(const float4*)(binp + r * FF + kc * 8 + 4);
        union { ushort s[8]; uint4 q; } u;
        u.s[0] = f2b(va.x); u.s[1] = f2b(va.y); u.s[2] = f2b(va.z); u.s[3] = f2b(va.w);
        u.s[4] = f2b(vb.x); u.s[5] = f2b(vb.y); u.s[6] = f2b(vb.z); u.s[7] = f2b(vb.w);
        *(uint4*)&Bs[kc * 520 + r * 8] = u.q;
    }
    __syncthreads();

    const ushort* A = WAp + hh * 32768;
    int nl = wave * 16 + l16;
    floatx4 acc[8];
    floatx4 zero = {0.f, 0.f, 0.f, 0.f};
#pragma unroll
    for (int mt = 0; mt < 8; mt++) acc[mt] = zero;

#pragma unroll 2
    for (int kc2 = 0; kc2 < 8; kc2++) {
        int kc = kc2 * 4 + quad;
        short8 bfr = *(const short8*)&Bs[kc * 520 + nl * 8];
#pragma unroll
        for (int mt = 0; mt < 8; mt++) {
            short8 af = *(const short8*)(A + kc * 1024 + (mt * 16 + l16) * 8);
            acc[mt] = __builtin_amdgcn_mfma_f32_16x16x32_bf16(af, bfr, acc[mt], 0, 0, 0);
        }
    }

    const float* a1 = a1g + hh * OO;
    const float* a2 = a2g + hh * OO;
    float sp1 = 0.f, sp2 = 0.f;
#pragma unroll
    for (int mt = 0; mt < 8; mt++) {
        float4 v1 = *(const float4*)(a1 + mt * 16 + quad * 4);
        float4 v2 = *(const float4*)(a2 + mt * 16 + quad * 4);
        sp1 += acc[mt][0] * v1.x + acc[mt][1] * v1.y + acc[mt][2] * v1.z + acc[mt][3] * v1.w;
        sp2 += acc[mt][0] * v2.x + acc[mt][1] * v2.y + acc[mt][2] * v2.z + acc[mt][3] * v2.w;
    }
    sp1 += __shfl_xor(sp1, 16); sp1 += __shfl_xor(sp1, 32);
    sp2 += __shfl_xor(sp2, 16); sp2 += __shfl_xor(sp2, 32);
    if (lane < 16) {
        s1[(long)bh * NN + n0w + l16] = sp1;
        s2[(long)bh * NN + n0w + l16] = sp2;
    }

    ushort* cb = Cb + (long)bh * OO * NN;
    int n = n0w + l16;
    int base = (n >> 3) * 1024 + (n & 7);
#pragma unroll
    for (int mt = 0; mt < 8; mt++) {
#pragma unroll
        for (int reg = 0; reg < 4; reg++) {
            int o = mt * 16 + quad * 4 + reg;
            cb[base + o * 8] = f2b(acc[mt][reg]);
        }
    }
}

// ---------------- layer-1: split-K GEMM, packed A (WOp) + packed B (x_b) ----
__global__ __launch_bounds__(256) void gemmT_sk(
    const ushort* __restrict__ WOp, const ushort* __restrict__ Bb,
    ushort* __restrict__ Cb, float* __restrict__ s1, float* __restrict__ s2,
    const float* __restrict__ a1g, const float* __restrict__ a2g)
{
    __shared__ float red[4 * 2304];   // 36,864 B
    int t = threadIdx.x;
    int wave = t >> 6, lane = t & 63;
    int quad = lane >> 4, l16 = lane & 15;
    int b = blockIdx.y;
    int n0 = blockIdx.x * 16;

    long rb = ((long)b * NN + n0 + l16) * 8;   // packed row base
    int kbase = wave * 256;

    floatx4 acc[8];
    floatx4 zero = {0.f, 0.f, 0.f, 0.f};
#pragma unroll
    for (int mt = 0; mt < 8; mt++) acc[mt] = zero;

    for (int k0 = 0; k0 < 256; k0 += 32) {
        int kch = (kbase + k0 + quad * 8) >> 3;
        short8 bfr = *(const short8*)(Bb + (long)kch * 65536 + rb);
#pragma unroll
        for (int mt = 0; mt < 8; mt++) {
            short8 af = *(const short8*)(WOp + kch * 1024 + (mt * 16 + l16) * 8);
            acc[mt] = __builtin_amdgcn_mfma_f32_16x16x32_bf16(af, bfr, acc[mt], 0, 0, 0);
        }
    }

#pragma unroll
    for (int mt = 0; mt < 8; mt++)
#pragma unroll
        for (int reg = 0; reg < 4; reg++)
            red[wave * 2304 + (mt * 16 + quad * 4 + reg) * 18 + l16] = acc[mt][reg];
    __syncthreads();

    int nl = t & 15, g = t >> 4, o0 = g * 8;
    float s[8];
#pragma unroll
    for (int k = 0; k < 8; k++) {
        int idx = (o0 + k) * 18 + nl;
        s[k] = red[idx] + red[2304 + idx] + red[4608 + idx] + red[6912 + idx];
    }

    float p1 = 0.f, p2 = 0.f;
#pragma unroll
    for (int k = 0; k < 8; k++) {
        p1 += s[k] * a1g[o0 + k];
        p2 += s[k] * a2g[o0 + k];
    }

    ushort* cb = Cb + (long)b * OO * NN;
    int nglob = n0 + nl;
    int base = (nglob >> 3) * 1024 + (nglob & 7);
#pragma unroll
    for (int k = 0; k < 8; k++) cb[base + (o0 + k) * 8] = f2b(s[k]);

    __syncthreads();
    red[g * 16 + nl] = p1;
    red[256 + g * 16 + nl] = p2;
    __syncthreads();
    if (t < 16) {
        float q1 = 0.f, q2 = 0.f;
#pragma unroll
        for (int gg = 0; gg < 16; gg++) {
            q1 += red[gg * 16 + t];
            q2 += red[256 + gg * 16 + t];
        }
        s1[(long)b * NN + n0 + t] = q1;
        s2[(long)b * NN + n0 + t] = q2;
    }
}

// ---------------- single-pass masked-softmax attention + MFMA PV ------------
// e^(i,j) = adjbit ? exp(lrelu(s1_i+s2_j)) : 0. A-fragments bit-identical to
// R9/R10 (shift truncation). NEW: L accumulated by MFMA vs const-ones
// B-fragment -> no Lp adds, no truncation ANDs, no epilogue shuffles.
// writeBf=1 path stores x fragment-packed (chunk stride 65536).
// dyn LDS: s2s[1024] | red[8448] (stride 132) | Lred[64]  = 38,144 B
template <int JS>
__global__ __launch_bounds__(256) void attn_mfma(
    const float* __restrict__ s1g, const float* __restrict__ s2g,
    const ushort* __restrict__ hTp, const uint* __restrict__ adjp,
    float* __restrict__ outf, ushort* __restrict__ outb,
    int Hh, int outStride, int doElu, int writeBf)
{
    extern __shared__ float smem_f[];
    float* s2s = smem_f;
    float* red = smem_f + NN;
    float* Lred = red + 8448;

    int t = threadIdx.x;
    int wave = t >> 6, lane = t & 63;
    int quad = lane >> 4, l16 = lane & 15;
    int bh = blockIdx.y;
    int hh = bh % Hh, b = bh / Hh;

    const float* s2r = s2g + (long)bh * NN;
    for (int j = t; j < NN; j += 256) s2s[j] = s2r[j];
    __syncthreads();

    const ushort* hT = hTp + (long)bh * OO * NN;
    const ushort* hbase = hT + quad * 1024 + l16 * 8;
    floatx4 zero = {0.f, 0.f, 0.f, 0.f};
    short8 ones8;
#pragma unroll
    for (int i = 0; i < 8; i++) ones8[i] = (short)0x3F80;   // bf16 1.0

    if (JS == 2) {
        int ig = wave >> 1, jh = wave & 1;
        int i0 = blockIdx.x * 64 + ig * 32;
        int j_lo = jh * (NN / 2), j_hi = j_lo + NN / 2;

        float s1a = s1g[(long)bh * NN + i0 + l16];
        float s1b = s1g[(long)bh * NN + i0 + 16 + l16];
        const uint* abA = adjp + ((long)b * NN + i0 + l16) * 32;
        const uint* abB = abA + 16 * 32;

        floatx4 acc0[8], acc1[8], accL0 = zero, accL1 = zero;
#pragma unroll
        for (int ot = 0; ot < 8; ot++) { acc0[ot] = zero; acc1[ot] = zero; }

        for (int j0 = j_lo; j0 < j_hi; j0 += 32) {
            const ushort* hp = hbase + (j0 >> 3) * 1024;
            short8 bf[8];
#pragma unroll
            for (int ot = 0; ot < 8; ot++)
                bf[ot] = *(const short8*)(hp + ot * 128);
            uint mbA = (abA[j0 >> 5] >> (quad * 8)) & 0xffu;
            uint mbB = (abB[j0 >> 5] >> (quad * 8)) & 0xffu;
            int kb = j0 + quad * 8;
            float4 sA4 = *(const float4*)(s2s + kb);
            float4 sB4 = *(const float4*)(s2s + kb + 4);
            float se[8] = {sA4.x, sA4.y, sA4.z, sA4.w, sB4.x, sB4.y, sB4.z, sB4.w};
            short8 afA, afB;
#pragma unroll
            for (int e = 0; e < 8; e++) {
                float ea = s1a + se[e]; ea = fmaxf(ea, 0.2f * ea);
                float eb = s1b + se[e]; eb = fmaxf(eb, 0.2f * eb);
                union { float f; uint u; } wa, wb;
                wa.f = ((mbA >> e) & 1u) ? __expf(ea) : 0.f;
                wb.f = ((mbB >> e) & 1u) ? __expf(eb) : 0.f;
                afA[e] = (short)(wa.u >> 16);   // truncate to bf16
                afB[e] = (short)(wb.u >> 16);
            }
#pragma unroll
            for (int ot = 0; ot < 8; ot++) {
                acc0[ot] = __builtin_amdgcn_mfma_f32_16x16x32_bf16(afA, bf[ot], acc0[ot], 0, 0, 0);
                acc1[ot] = __builtin_amdgcn_mfma_f32_16x16x32_bf16(afB, bf[ot], acc1[ot], 0, 0, 0);
            }
            accL0 = __builtin_amdgcn_mfma_f32_16x16x32_bf16(afA, ones8, accL0, 0, 0, 0);
            accL1 = __builtin_amdgcn_mfma_f32_16x16x32_bf16(afB, ones8, accL1, 0, 0, 0);
        }

        if (jh == 1) {
#pragma unroll
            for (int ot = 0; ot < 8; ot++)
#pragma unroll
                for (int reg = 0; reg < 4; reg++) {
                    red[(ig * 32 + quad * 4 + reg) * 132 + ot * 16 + l16] = acc0[ot][reg];
                    red[(ig * 32 + 16 + quad * 4 + reg) * 132 + ot * 16 + l16] = acc1[ot][reg];
                }
            if (l16 == 0) {
#pragma unroll
                for (int reg = 0; reg < 4; reg++) {
                    Lred[(ig * 2 + 0) * 16 + quad * 4 + reg] = accL0[reg];
                    Lred[(ig * 2 + 1) * 16 + quad * 4 + reg] = accL1[reg];
                }
            }
        }
        __syncthreads();
        if (jh == 0) {
#pragma unroll
            for (int tile = 0; tile < 2; tile++) {
                floatx4 acL = tile ? accL1 : accL0;
                floatx4* ac = tile ? acc1 : acc0;
#pragma unroll
                for (int reg = 0; reg < 4; reg++) {
                    float Lsum = acL[reg] + Lred[(ig * 2 + tile) * 16 + quad * 4 + reg];
                    float linv = 1.0f / Lsum;
                    int rloc = ig * 32 + tile * 16 + quad * 4 + reg;
                    int row = blockIdx.x * 64 + rloc;
                    if (writeBf) {
                        long rg = (long)b * NN + row;
#pragma unroll
                        for (int ot = 0; ot < 8; ot++) {
                            float v = (ac[ot][reg] + red[rloc * 132 + ot * 16 + l16]) * linv;
                            if (doElu) v = (v > 0.f) ? v : (__expf(v) - 1.0f);
                            int col = hh * OO + ot * 16 + l16;
                            outb[(long)(col >> 3) * 65536 + rg * 8 + (col & 7)] = f2b(v);
                        }
                    } else {
                        float* orow = outf + (long)b * NN * outStride + hh * OO +
                                      (long)row * outStride + l16;
#pragma unroll
                        for (int ot = 0; ot < 8; ot++) {
                            float v = (ac[ot][reg] + red[rloc * 132 + ot * 16 + l16]) * linv;
                            if (doElu) v = (v > 0.f) ? v : (__expf(v) - 1.0f);
                            orow[ot * 16] = v;
                        }
                    }
                }
            }
        }
    } else {   // JS == 4
        int i0 = blockIdx.x * 16;
        int j_lo = wave * (NN / 4), j_hi = j_lo + NN / 4;

        float s1a = s1g[(long)bh * NN + i0 + l16];
        const uint* abA = adjp + ((long)b * NN + i0 + l16) * 32;

        floatx4 acc[8], accL = zero;
#pragma unroll
        for (int ot = 0; ot < 8; ot++) acc[ot] = zero;

        for (int j0 = j_lo; j0 < j_hi; j0 += 32) {
            const ushort* hp = hbase + (j0 >> 3) * 1024;
            short8 bf[8];
#pragma unroll
            for (int ot = 0; ot < 8; ot++)
                bf[ot] = *(const short8*)(hp + ot * 128);
            uint mbA = (abA[j0 >> 5] >> (quad * 8)) & 0xffu;
            int kb = j0 + quad * 8;
            float4 sA4 = *(const float4*)(s2s + kb);
            float4 sB4 = *(const float4*)(s2s + kb + 4);
            float se[8] = {sA4.x, sA4.y, sA4.z, sA4.w, sB4.x, sB4.y, sB4.z, sB4.w};
            short8 afA;
#pragma unroll
            for (int e = 0; e < 8; e++) {
                float ea = s1a + se[e]; ea = fmaxf(ea, 0.2f * ea);
                union { float f; uint u; } wa;
                wa.f = ((mbA >> e) & 1u) ? __expf(ea) : 0.f;
                afA[e] = (short)(wa.u >> 16);
            }
#pragma unroll
            for (int ot = 0; ot < 8; ot++)
                acc[ot] = __builtin_amdgcn_mfma_f32_16x16x32_bf16(afA, bf[ot], acc[ot], 0, 0, 0);
            accL = __builtin_amdgcn_mfma_f32_16x16x32_bf16(afA, ones8, accL, 0, 0, 0);
        }

#pragma unroll
        for (int ot = 0; ot < 8; ot++)
#pragma unroll
            for (int reg = 0; reg < 4; reg++)
                red[(wave * 16 + quad * 4 + reg) * 132 + ot * 16 + l16] = acc[ot][reg];
        if (l16 == 0) {
#pragma unroll
            for (int reg = 0; reg < 4; reg++)
                Lred[wave * 16 + quad * 4 + reg] = accL[reg];
        }
        __syncthreads();
        int row = t >> 4, c0 = (t & 15) * 8;
        float L = Lred[row] + Lred[16 + row] + Lred[32 + row] + Lred[48 + row];
        float rinv = 1.0f / L;
        int grow = i0 + row;
        float vv[8];
#pragma unroll
        for (int k = 0; k < 8; k++) {
            float s = red[row * 132 + c0 + k] + red[(16 + row) * 132 + c0 + k] +
                      red[(32 + row) * 132 + c0 + k] + red[(48 + row) * 132 + c0 + k];
            float v = s * rinv;
            if (doElu) v = (v > 0.f) ? v : (__expf(v) - 1.0f);
            vv[k] = v;
        }
        if (writeBf) {
            ushort* orow = outb + (long)b * NN * outStride + hh * OO +
                           (long)grow * outStride + c0;
#pragma unroll
            for (int k = 0; k < 8; k++) orow[k] = f2b(vv[k]);
        } else {
            float* orow = outf + (long)b * NN * outStride + hh * OO +
                          (long)grow * outStride + c0;
            *(float4*)orow = make_float4(vv[0], vv[1], vv[2], vv[3]);
            *(float4*)(orow + 4) = make_float4(vv[4], vv[5], vv[6], vv[7]);
        }
    }
}

// ---------------- final: y = x@lin_w.T+lin_b+out2; out = relu(y@ln_w.T+ln_b)
// A (x_b) packed: 256B-contiguous/quad. B (LWp/NWp) packed.
__global__ __launch_bounds__(256) void final_mfma(
    const ushort* __restrict__ xb, const float* __restrict__ out2,
    const ushort* __restrict__ LWp, const float* __restrict__ lin_b,
    const ushort* __restrict__ NWp, const float* __restrict__ ln_b,
    float* __restrict__ out)
{
    __shared__ ushort ys[32][136];
    int t = threadIdx.x;
    int wave = t >> 6, lane = t & 63;
    int quad = lane >> 4, l16 = lane & 15;
    long row0 = (long)blockIdx.x * 32;
    int n0 = wave * 32;

    floatx4 zero = {0.f, 0.f, 0.f, 0.f};
    floatx4 acc[2][2];
#pragma unroll
    for (int mt = 0; mt < 2; mt++)
#pragma unroll
        for (int nt = 0; nt < 2; nt++) acc[mt][nt] = zero;

    for (int k0 = 0; k0 < HO; k0 += 32) {
        int kch = (k0 + quad * 8) >> 3;
        short8 a0 = *(const short8*)(xb + (long)kch * 65536 + (row0 + l16) * 8);
        short8 a1 = *(const short8*)(xb + (long)kch * 65536 + (row0 + 16 + l16) * 8);
        short8 b0 = *(const short8*)(LWp + kch * 1024 + (n0 + l16) * 8);
        short8 b1 = *(const short8*)(LWp + kch * 1024 + (n0 + 16 + l16) * 8);
        acc[0][0] = __builtin_amdgcn_mfma_f32_16x16x32_bf16(a0, b0, acc[0][0], 0, 0, 0);
        acc[0][1] = __builtin_amdgcn_mfma_f32_16x16x32_bf16(a0, b1, acc[0][1], 0, 0, 0);
        acc[1][0] = __builtin_amdgcn_mfma_f32_16x16x32_bf16(a1, b0, acc[1][0], 0, 0, 0);
        acc[1][1] = __builtin_amdgcn_mfma_f32_16x16x32_bf16(a1, b1, acc[1][1], 0, 0, 0);
    }

#pragma unroll
    for (int nt = 0; nt < 2; nt++) {
        int col = n0 + nt * 16 + l16;
        float lb = lin_b[col];
#pragma unroll
        for (int mt = 0; mt < 2; mt++) {
#pragma unroll
            for (int reg = 0; reg < 4; reg++) {
                int row = mt * 16 + quad * 4 + reg;
                float v = acc[mt][nt][reg] + lb + out2[(row0 + row) * OO + col];
                ys[row][col] = f2b(v);
            }
        }
    }
    __syncthreads();

    floatx4 acc2[2][2];
#pragma unroll
    for (int mt = 0; mt < 2; mt++)
#pragma unroll
        for (int nt = 0; nt < 2; nt++) acc2[mt][nt] = zero;

#pragma unroll
    for (int k0 = 0; k0 < OO; k0 += 32) {
        int kb = k0 + quad * 8;
        int kch = kb >> 3;
        short8 a0 = *(const short8*)&ys[l16][kb];
        short8 a1 = *(const short8*)&ys[16 + l16][kb];
        short8 b0 = *(const short8*)(NWp + kch * 1024 + (n0 + l16) * 8);
        short8 b1 = *(const short8*)(NWp + kch * 1024 + (n0 + 16 + l16) * 8);
        acc2[0][0] = __builtin_amdgcn_mfma_f32_16x16x32_bf16(a0, b0, acc2[0][0], 0, 0, 0);
        acc2[0][1] = __builtin_amdgcn_mfma_f32_16x16x32_bf16(a0, b1, acc2[0][1], 0, 0, 0);
        acc2[1][0] = __builtin_amdgcn_mfma_f32_16x16x32_bf16(a1, b0, acc2[1][0], 0, 0, 0);
        acc2[1][1] = __builtin_amdgcn_mfma_f32_16x16x32_bf16(a1, b1, acc2[1][1], 0, 0, 0);
    }

#pragma unroll
    for (int nt = 0; nt < 2; nt++) {
        int col = n0 + nt * 16 + l16;
        float nb = ln_b[col];
#pragma unroll
        for (int mt = 0; mt < 2; mt++) {
#pragma unroll
            for (int reg = 0; reg < 4; reg++) {
                int row = mt * 16 + quad * 4 + reg;
                out[(row0 + row) * OO + col] = fmaxf(acc2[mt][nt][reg] + nb, 0.f);
            }
        }
    }
}

extern "C" void kernel_launch(void* const* d_in, const int* in_sizes, int n_in,
                              void* d_out, int out_size, void* d_ws, size_t ws_size,
                              hipStream_t stream)
{
    const float* inputs = (const float*)d_in[0];
    const int*   adj    = (const int*)d_in[1];
    const float* W_att  = (const float*)d_in[3];
    const float* a_src  = (const float*)d_in[4];
    const float* a_dst  = (const float*)d_in[5];
    const float* W_out  = (const float*)d_in[6];
    const float* ao_src = (const float*)d_in[7];
    const float* ao_dst = (const float*)d_in[8];
    const float* lin_w  = (const float*)d_in[9];
    const float* lin_b  = (const float*)d_in[10];
    const float* ln_w   = (const float*)d_in[11];
    const float* ln_b   = (const float*)d_in[12];
    float* out = (float*)d_out;

    float* ws   = (float*)d_ws;
    float* out2 = ws;
    float* s1   = ws + 1048576;
    float* s2   = ws + 1114112;
    float* s1o  = ws + 1179648;
    float* s2o  = ws + 1187840;
    ushort* ub      = (ushort*)(ws + 1196032);
    ushort* x_b     = ub;
    ushort* h_catTb = ub + 8388608;
    ushort* h2Tb    = ub + 16777216;
    ushort* WAp     = ub + 17825792;
    ushort* WOp     = ub + 18087936;
    ushort* LWp     = ub + 18219008;
    ushort* NWp     = ub + 18350080;
    unsigned long long* adjp = (unsigned long long*)(ub + 18366464);

    const int SH = (NN + 8448 + 64) * 4;   // 38,144 B dyn LDS (attn)

    // 0. merged packing (adj bitmask + all weights)
    pack_all<<<2312, 256, 0, stream>>>(
        adj, adjp, W_att, W_out, lin_w, ln_w, WAp, WOp, LWp, NWp);
    // 1. h^T (packed) = (inputs @ W_att)^T per (b,h), bf16; fused s1/s2
    gemmT0<<<dim3(16, 64), 256, 0, stream>>>(
        WAp, inputs, h_catTb, s1, s2, a_src, a_dst);
    // 2. layer-0 attention -> x = elu(att@h) bf16, fragment-packed
    attn_mfma<2><<<dim3(16, 64), 256, SH, stream>>>(
        s1, s2, h_catTb, (const uint*)adjp, (float*)nullptr, x_b, HH, HO, 1, 1);
    // 3. h2^T (packed) = (x @ W_out)^T per b, split-K x4; fused s1o/s2o
    gemmT_sk<<<dim3(64, 8), 256, 0, stream>>>(
        WOp, x_b, h2Tb, s1o, s2o, ao_src, ao_dst);
    // 4. layer-1 attention -> out2 fp32 (no elu), j-split x4
    attn_mfma<4><<<dim3(64, 8), 256, SH, stream>>>(
        s1o, s2o, h2Tb, (const uint*)adjp, out2, (ushort*)nullptr, 1, OO, 0, 0);
    // 5. out = relu((x@lin_w.T + lin_b + out2) @ ln_w.T + ln_b)
    final_mfma<<<256, 256, 0, stream>>>(
        x_b, out2, LWp, lin_b, NWp, ln_b, out);
}

// Round 14
// 202.837 us; speedup vs baseline: 1.2312x; 1.0288x over previous
//
#include <hip/hip_runtime.h>

// GAT forward, MI355X. Round 13 = R12 with the cvt_pkrtz type fix
// (__fp16 ext_vector(2) union member; bit-identical layout).
//  (1) log2e pre-scale of s1/s2 + native exp2,
//  (2) A-fragments packed f16 via v_cvt_pkrtz; attn MFMAs f16;
//      h^T/h2^T stored f16. x_b stays bf16 for downstream bf16 GEMMs.
// B=8, N=1024, F=256, O=128, H=8, HO=1024, BH=64.
//
// packed layout (R rows x K cols): elem (r,k) at (k>>3)*(R*8) + r*8 + (k&7).
// x_b packed: R=8192, K=1024 -> chunk stride 65536.
// h^T packed per (b,h): elem (j,o) at (j>>3)*1024 + o*8 + (j&7)  [f16 bits].
//
// ws floats:
//   out2 [8192,128] @ 0        (1,048,576)
//   s1 @ 1048576  s2 @ 1114112 (65,536 each)
//   s1o @ 1179648 s2o @ 1187840 (8,192 each)
// ushort region @ float offset 1196032:
//   x_b(packed bf16) @ 0   h_catTb(f16) @ 8388608   h2Tb(f16) @ 16777216
//   WAp @ 17825792 (262144)   WOp @ 18087936 (131072)
//   LWp @ 18219008 (131072)   NWp @ 18350080 (16384)
//   adjp (ull[8192*16]) @ ushort 18366464  (1 MB)

#define NN 1024
#define FF 256
#define OO 128
#define HH 8
#define HO 1024
#define LOG2E 1.44269504f

typedef __attribute__((ext_vector_type(8))) short short8;
typedef __attribute__((ext_vector_type(8))) _Float16 half8;
typedef __attribute__((ext_vector_type(2))) __fp16 fp16x2;
typedef __attribute__((ext_vector_type(4))) float floatx4;

extern "C" __device__ float __ocml_native_exp2_f32(float);

__device__ __forceinline__ ushort f2b(float f) {
    union { float f; unsigned u; } v; v.f = f;
    unsigned r = v.u + 0x7FFFu + ((v.u >> 16) & 1u);   // RNE
    return (ushort)(r >> 16);
}
__device__ __forceinline__ ushort f2h_bits(float f) {
    union { _Float16 h; ushort u; } c; c.h = (_Float16)f;   // RNE cvt
    return c.u;
}

// ---------------- merged packing: adj bitmask + all weights -----------------
__global__ __launch_bounds__(256) void pack_all(
    const int* __restrict__ adj, unsigned long long* __restrict__ adjp,
    const float* __restrict__ W_att, const float* __restrict__ W_out,
    const float* __restrict__ lin_w, const float* __restrict__ ln_w,
    ushort* __restrict__ WAp, ushort* __restrict__ WOp,
    ushort* __restrict__ LWp, ushort* __restrict__ NWp)
{
    if (blockIdx.x < 2048) {
        int w = blockIdx.x * 4 + (threadIdx.x >> 6);
        int lane = threadIdx.x & 63;
        const int* row = adj + (long)w * NN;
#pragma unroll
        for (int it = 0; it < 16; it++) {
            unsigned long long m = __ballot(row[it * 64 + lane] > 0);
            if (lane == 0) adjp[(long)w * 16 + it] = m;
        }
        return;
    }
    int tid = (blockIdx.x - 2048) * 256 + threadIdx.x;
    float v[8];
    ushort* dst;
    if (tid < 32768) {                       // W_att [8][256][128]
        int h = tid >> 12, rem = tid & 4095, kc = rem >> 7, o = rem & 127;
        const float* s = W_att + h * 32768;
#pragma unroll
        for (int i = 0; i < 8; i++) v[i] = s[(kc * 8 + i) * 128 + o];
        dst = WAp + h * 32768 + kc * 1024 + o * 8;
    } else if (tid < 49152) {                // W_out [1024][128]
        int t2 = tid - 32768;
        int kc = t2 >> 7, o = t2 & 127;
#pragma unroll
        for (int i = 0; i < 8; i++) v[i] = W_out[(kc * 8 + i) * 128 + o];
        dst = WOp + kc * 1024 + o * 8;
    } else if (tid < 65536) {                // lin_w [128][1024]
        int t3 = tid - 49152;
        int kc = t3 >> 7, c = t3 & 127;
        float4 a = *(const float4*)(lin_w + c * 1024 + kc * 8);
        float4 bq = *(const float4*)(lin_w + c * 1024 + kc * 8 + 4);
        v[0] = a.x; v[1] = a.y; v[2] = a.z; v[3] = a.w;
        v[4] = bq.x; v[5] = bq.y; v[6] = bq.z; v[7] = bq.w;
        dst = LWp + kc * 1024 + c * 8;
    } else {                                 // ln_w [128][128]
        int t4 = tid - 65536;
        int kc = t4 >> 7, c = t4 & 127;
        float4 a = *(const float4*)(ln_w + c * 128 + kc * 8);
        float4 bq = *(const float4*)(ln_w + c * 128 + kc * 8 + 4);
        v[0] = a.x; v[1] = a.y; v[2] = a.z; v[3] = a.w;
        v[4] = bq.x; v[5] = bq.y; v[6] = bq.z; v[7] = bq.w;
        dst = NWp + kc * 1024 + c * 8;
    }
    union { ushort s[8]; uint4 q; } u;
#pragma unroll
    for (int i = 0; i < 8; i++) u.s[i] = f2b(v[i]);
    *(uint4*)dst = u.q;
}

// ---------------- layer-0 GEMM: packed-A weights + LDS-staged packed B ------
// bf16 MFMA; h^T output stored as f16 bits (for f16 attn).
__global__ __launch_bounds__(256) void gemmT0(
    const ushort* __restrict__ WAp, const float* __restrict__ inputs,
    ushort* __restrict__ Cb, float* __restrict__ s1, float* __restrict__ s2,
    const float* __restrict__ a1g, const float* __restrict__ a2g)
{
    __shared__ ushort Bs[32 * 520];   // 33,280 B
    int t = threadIdx.x;
    int wave = t >> 6, lane = t & 63;
    int quad = lane >> 4, l16 = lane & 15;
    int bh = blockIdx.y;
    int hh = bh & 7, b = bh >> 3;
    int nblk = blockIdx.x * 64;
    int n0w = nblk + wave * 16;

    const float* binp = inputs + ((long)b * NN + nblk) * FF;
#pragma unroll
    for (int it = 0; it < 8; it++) {
        int pid = it * 256 + t;
        int kc = pid & 31, r = pid >> 5;
        float4 va = *(const float4*)(binp + r * FF + kc * 8);
        float4 vb = *(const float4*)(binp + r * FF + kc * 8 + 4);
        union { ushort s[8]; uint4 q; } u;
        u.s[0] = f2b(va.x); u.s[1] = f2b(va.y); u.s[2] = f2b(va.z); u.s[3] = f2b(va.w);
        u.s[4] = f2b(vb.x); u.s[5] = f2b(vb.y); u.s[6] = f2b(vb.z); u.s[7] = f2b(vb.w);
        *(uint4*)&Bs[kc * 520 + r * 8] = u.q;
    }
    __syncthreads();

    const ushort* A = WAp + hh * 32768;
    int nl = wave * 16 + l16;
    floatx4 acc[8];
    floatx4 zero = {0.f, 0.f, 0.f, 0.f};
#pragma unroll
    for (int mt = 0; mt < 8; mt++) acc[mt] = zero;

#pragma unroll 2
    for (int kc2 = 0; kc2 < 8; kc2++) {
        int kc = kc2 * 4 + quad;
        short8 bfr = *(const short8*)&Bs[kc * 520 + nl * 8];
#pragma unroll
        for (int mt = 0; mt < 8; mt++) {
            short8 af = *(const short8*)(A + kc * 1024 + (mt * 16 + l16) * 8);
            acc[mt] = __builtin_amdgcn_mfma_f32_16x16x32_bf16(af, bfr, acc[mt], 0, 0, 0);
        }
    }

    const float* a1 = a1g + hh * OO;
    const float* a2 = a2g + hh * OO;
    float sp1 = 0.f, sp2 = 0.f;
#pragma unroll
    for (int mt = 0; mt < 8; mt++) {
        float4 v1 = *(const float4*)(a1 + mt * 16 + quad * 4);
        float4 v2 = *(const float4*)(a2 + mt * 16 + quad * 4);
        sp1 += acc[mt][0] * v1.x + acc[mt][1] * v1.y + acc[mt][2] * v1.z + acc[mt][3] * v1.w;
        sp2 += acc[mt][0] * v2.x + acc[mt][1] * v2.y + acc[mt][2] * v2.z + acc[mt][3] * v2.w;
    }
    sp1 += __shfl_xor(sp1, 16); sp1 += __shfl_xor(sp1, 32);
    sp2 += __shfl_xor(sp2, 16); sp2 += __shfl_xor(sp2, 32);
    if (lane < 16) {
        s1[(long)bh * NN + n0w + l16] = sp1;
        s2[(long)bh * NN + n0w + l16] = sp2;
    }

    ushort* cb = Cb + (long)bh * OO * NN;
    int n = n0w + l16;
    int base = (n >> 3) * 1024 + (n & 7);
#pragma unroll
    for (int mt = 0; mt < 8; mt++) {
#pragma unroll
        for (int reg = 0; reg < 4; reg++) {
            int o = mt * 16 + quad * 4 + reg;
            cb[base + o * 8] = f2h_bits(acc[mt][reg]);
        }
    }
}

// ---------------- layer-1: split-K GEMM, packed A (WOp) + packed B (x_b) ----
// bf16 MFMA; h2^T output stored as f16 bits.
__global__ __launch_bounds__(256) void gemmT_sk(
    const ushort* __restrict__ WOp, const ushort* __restrict__ Bb,
    ushort* __restrict__ Cb, float* __restrict__ s1, float* __restrict__ s2,
    const float* __restrict__ a1g, const float* __restrict__ a2g)
{
    __shared__ float red[4 * 2304];   // 36,864 B
    int t = threadIdx.x;
    int wave = t >> 6, lane = t & 63;
    int quad = lane >> 4, l16 = lane & 15;
    int b = blockIdx.y;
    int n0 = blockIdx.x * 16;

    long rb = ((long)b * NN + n0 + l16) * 8;
    int kbase = wave * 256;

    floatx4 acc[8];
    floatx4 zero = {0.f, 0.f, 0.f, 0.f};
#pragma unroll
    for (int mt = 0; mt < 8; mt++) acc[mt] = zero;

    for (int k0 = 0; k0 < 256; k0 += 32) {
        int kch = (kbase + k0 + quad * 8) >> 3;
        short8 bfr = *(const short8*)(Bb + (long)kch * 65536 + rb);
#pragma unroll
        for (int mt = 0; mt < 8; mt++) {
            short8 af = *(const short8*)(WOp + kch * 1024 + (mt * 16 + l16) * 8);
            acc[mt] = __builtin_amdgcn_mfma_f32_16x16x32_bf16(af, bfr, acc[mt], 0, 0, 0);
        }
    }

#pragma unroll
    for (int mt = 0; mt < 8; mt++)
#pragma unroll
        for (int reg = 0; reg < 4; reg++)
            red[wave * 2304 + (mt * 16 + quad * 4 + reg) * 18 + l16] = acc[mt][reg];
    __syncthreads();

    int nl = t & 15, g = t >> 4, o0 = g * 8;
    float s[8];
#pragma unroll
    for (int k = 0; k < 8; k++) {
        int idx = (o0 + k) * 18 + nl;
        s[k] = red[idx] + red[2304 + idx] + red[4608 + idx] + red[6912 + idx];
    }

    float p1 = 0.f, p2 = 0.f;
#pragma unroll
    for (int k = 0; k < 8; k++) {
        p1 += s[k] * a1g[o0 + k];
        p2 += s[k] * a2g[o0 + k];
    }

    ushort* cb = Cb + (long)b * OO * NN;
    int nglob = n0 + nl;
    int base = (nglob >> 3) * 1024 + (nglob & 7);
#pragma unroll
    for (int k = 0; k < 8; k++) cb[base + (o0 + k) * 8] = f2h_bits(s[k]);

    __syncthreads();
    red[g * 16 + nl] = p1;
    red[256 + g * 16 + nl] = p2;
    __syncthreads();
    if (t < 16) {
        float q1 = 0.f, q2 = 0.f;
#pragma unroll
        for (int gg = 0; gg < 16; gg++) {
            q1 += red[gg * 16 + t];
            q2 += red[256 + gg * 16 + t];
        }
        s1[(long)b * NN + n0 + t] = q1;
        s2[(long)b * NN + n0 + t] = q2;
    }
}

// ---------------- single-pass masked-softmax attention + f16 MFMA PV --------
// w(i,j) = adjbit ? 2^(lrelu(s1'+s2')) : 0, s' = log2e*s (lrelu pos-homog).
// A-fragments f16 via v_cvt_pkrtz; h^T is f16. L via MFMA vs ones.
// dyn LDS: s2s[1024] | red[8448] (stride 132) | Lred[64]  = 38,144 B
template <int JS>
__global__ __launch_bounds__(256) void attn_mfma(
    const float* __restrict__ s1g, const float* __restrict__ s2g,
    const ushort* __restrict__ hTp, const uint* __restrict__ adjp,
    float* __restrict__ outf, ushort* __restrict__ outb,
    int Hh, int outStride, int doElu, int writeBf)
{
    extern __shared__ float smem_f[];
    float* s2s = smem_f;
    float* red = smem_f + NN;
    float* Lred = red + 8448;

    int t = threadIdx.x;
    int wave = t >> 6, lane = t & 63;
    int quad = lane >> 4, l16 = lane & 15;
    int bh = blockIdx.y;
    int hh = bh % Hh, b = bh / Hh;

    const float* s2r = s2g + (long)bh * NN;
    for (int j = t; j < NN; j += 256) s2s[j] = LOG2E * s2r[j];
    __syncthreads();

    const ushort* hT = hTp + (long)bh * OO * NN;
    const ushort* hbase = hT + quad * 1024 + l16 * 8;
    floatx4 zero = {0.f, 0.f, 0.f, 0.f};
    half8 ones8;
#pragma unroll
    for (int i = 0; i < 8; i++) ones8[i] = (_Float16)1.0f;

    if (JS == 2) {
        int ig = wave >> 1, jh = wave & 1;
        int i0 = blockIdx.x * 64 + ig * 32;
        int j_lo = jh * (NN / 2), j_hi = j_lo + NN / 2;

        float s1a = LOG2E * s1g[(long)bh * NN + i0 + l16];
        float s1b = LOG2E * s1g[(long)bh * NN + i0 + 16 + l16];
        const uint* abA = adjp + ((long)b * NN + i0 + l16) * 32;
        const uint* abB = abA + 16 * 32;

        floatx4 acc0[8], acc1[8], accL0 = zero, accL1 = zero;
#pragma unroll
        for (int ot = 0; ot < 8; ot++) { acc0[ot] = zero; acc1[ot] = zero; }

        for (int j0 = j_lo; j0 < j_hi; j0 += 32) {
            const ushort* hp = hbase + (j0 >> 3) * 1024;
            half8 bf[8];
#pragma unroll
            for (int ot = 0; ot < 8; ot++)
                bf[ot] = *(const half8*)(hp + ot * 128);
            uint mbA = (abA[j0 >> 5] >> (quad * 8)) & 0xffu;
            uint mbB = (abB[j0 >> 5] >> (quad * 8)) & 0xffu;
            int kb = j0 + quad * 8;
            float4 sA4 = *(const float4*)(s2s + kb);
            float4 sB4 = *(const float4*)(s2s + kb + 4);
            float se[8] = {sA4.x, sA4.y, sA4.z, sA4.w, sB4.x, sB4.y, sB4.z, sB4.w};
            union { fp16x2 h2[4]; half8 h8; } ua, ub;
#pragma unroll
            for (int pr = 0; pr < 4; pr++) {
                float wv[2][2];
#pragma unroll
                for (int h = 0; h < 2; h++) {
                    int e = pr * 2 + h;
                    float ea = s1a + se[e]; ea = fmaxf(ea, 0.2f * ea);
                    float eb = s1b + se[e]; eb = fmaxf(eb, 0.2f * eb);
                    wv[0][h] = ((mbA >> e) & 1u) ? __ocml_native_exp2_f32(ea) : 0.f;
                    wv[1][h] = ((mbB >> e) & 1u) ? __ocml_native_exp2_f32(eb) : 0.f;
                }
                ua.h2[pr] = __builtin_amdgcn_cvt_pkrtz(wv[0][0], wv[0][1]);
                ub.h2[pr] = __builtin_amdgcn_cvt_pkrtz(wv[1][0], wv[1][1]);
            }
#pragma unroll
            for (int ot = 0; ot < 8; ot++) {
                acc0[ot] = __builtin_amdgcn_mfma_f32_16x16x32_f16(ua.h8, bf[ot], acc0[ot], 0, 0, 0);
                acc1[ot] = __builtin_amdgcn_mfma_f32_16x16x32_f16(ub.h8, bf[ot], acc1[ot], 0, 0, 0);
            }
            accL0 = __builtin_amdgcn_mfma_f32_16x16x32_f16(ua.h8, ones8, accL0, 0, 0, 0);
            accL1 = __builtin_amdgcn_mfma_f32_16x16x32_f16(ub.h8, ones8, accL1, 0, 0, 0);
        }

        if (jh == 1) {
#pragma unroll
            for (int ot = 0; ot < 8; ot++)
#pragma unroll
                for (int reg = 0; reg < 4; reg++) {
                    red[(ig * 32 + quad * 4 + reg) * 132 + ot * 16 + l16] = acc0[ot][reg];
                    red[(ig * 32 + 16 + quad * 4 + reg) * 132 + ot * 16 + l16] = acc1[ot][reg];
                }
            if (l16 == 0) {
#pragma unroll
                for (int reg = 0; reg < 4; reg++) {
                    Lred[(ig * 2 + 0) * 16 + quad * 4 + reg] = accL0[reg];
                    Lred[(ig * 2 + 1) * 16 + quad * 4 + reg] = accL1[reg];
                }
            }
        }
        __syncthreads();
        if (jh == 0) {
#pragma unroll
            for (int tile = 0; tile < 2; tile++) {
                floatx4 acL = tile ? accL1 : accL0;
                floatx4* ac = tile ? acc1 : acc0;
#pragma unroll
                for (int reg = 0; reg < 4; reg++) {
                    float Lsum = acL[reg] + Lred[(ig * 2 + tile) * 16 + quad * 4 + reg];
                    float linv = 1.0f / Lsum;
                    int rloc = ig * 32 + tile * 16 + quad * 4 + reg;
                    int row = blockIdx.x * 64 + rloc;
                    if (writeBf) {
                        long rg = (long)b * NN + row;
#pragma unroll
                        for (int ot = 0; ot < 8; ot++) {
                            float v = (ac[ot][reg] + red[rloc * 132 + ot * 16 + l16]) * linv;
                            if (doElu) v = (v > 0.f) ? v : (__expf(v) - 1.0f);
                            int col = hh * OO + ot * 16 + l16;
                            outb[(long)(col >> 3) * 65536 + rg * 8 + (col & 7)] = f2b(v);
                        }
                    } else {
                        float* orow = outf + (long)b * NN * outStride + hh * OO +
                                      (long)row * outStride + l16;
#pragma unroll
                        for (int ot = 0; ot < 8; ot++) {
                            float v = (ac[ot][reg] + red[rloc * 132 + ot * 16 + l16]) * linv;
                            if (doElu) v = (v > 0.f) ? v : (__expf(v) - 1.0f);
                            orow[ot * 16] = v;
                        }
                    }
                }
            }
        }
    } else {   // JS == 4
        int i0 = blockIdx.x * 16;
        int j_lo = wave * (NN / 4), j_hi = j_lo + NN / 4;

        float s1a = LOG2E * s1g[(long)bh * NN + i0 + l16];
        const uint* abA = adjp + ((long)b * NN + i0 + l16) * 32;

        floatx4 acc[8], accL = zero;
#pragma unroll
        for (int ot = 0; ot < 8; ot++) acc[ot] = zero;

        for (int j0 = j_lo; j0 < j_hi; j0 += 32) {
            const ushort* hp = hbase + (j0 >> 3) * 1024;
            half8 bf[8];
#pragma unroll
            for (int ot = 0; ot < 8; ot++)
                bf[ot] = *(const half8*)(hp + ot * 128);
            uint mbA = (abA[j0 >> 5] >> (quad * 8)) & 0xffu;
            int kb = j0 + quad * 8;
            float4 sA4 = *(const float4*)(s2s + kb);
            float4 sB4 = *(const float4*)(s2s + kb + 4);
            float se[8] = {sA4.x, sA4.y, sA4.z, sA4.w, sB4.x, sB4.y, sB4.z, sB4.w};
            union { fp16x2 h2[4]; half8 h8; } ua;
#pragma unroll
            for (int pr = 0; pr < 4; pr++) {
                float wv[2];
#pragma unroll
                for (int h = 0; h < 2; h++) {
                    int e = pr * 2 + h;
                    float ea = s1a + se[e]; ea = fmaxf(ea, 0.2f * ea);
                    wv[h] = ((mbA >> e) & 1u) ? __ocml_native_exp2_f32(ea) : 0.f;
                }
                ua.h2[pr] = __builtin_amdgcn_cvt_pkrtz(wv[0], wv[1]);
            }
#pragma unroll
            for (int ot = 0; ot < 8; ot++)
                acc[ot] = __builtin_amdgcn_mfma_f32_16x16x32_f16(ua.h8, bf[ot], acc[ot], 0, 0, 0);
            accL = __builtin_amdgcn_mfma_f32_16x16x32_f16(ua.h8, ones8, accL, 0, 0, 0);
        }

#pragma unroll
        for (int ot = 0; ot < 8; ot++)
#pragma unroll
            for (int reg = 0; reg < 4; reg++)
                red[(wave * 16 + quad * 4 + reg) * 132 + ot * 16 + l16] = acc[ot][reg];
        if (l16 == 0) {
#pragma unroll
            for (int reg = 0; reg < 4; reg++)
                Lred[wave * 16 + quad * 4 + reg] = accL[reg];
        }
        __syncthreads();
        int row = t >> 4, c0 = (t & 15) * 8;
        float L = Lred[row] + Lred[16 + row] + Lred[32 + row] + Lred[48 + row];
        float rinv = 1.0f / L;
        int grow = i0 + row;
        float vv[8];
#pragma unroll
        for (int k = 0; k < 8; k++) {
            float s = red[row * 132 + c0 + k] + red[(16 + row) * 132 + c0 + k] +
                      red[(32 + row) * 132 + c0 + k] + red[(48 + row) * 132 + c0 + k];
            float v = s * rinv;
            if (doElu) v = (v > 0.f) ? v : (__expf(v) - 1.0f);
            vv[k] = v;
        }
        if (writeBf) {
            ushort* orow = outb + (long)b * NN * outStride + hh * OO +
                           (long)grow * outStride + c0;
#pragma unroll
            for (int k = 0; k < 8; k++) orow[k] = f2b(vv[k]);
        } else {
            float* orow = outf + (long)b * NN * outStride + hh * OO +
                          (long)grow * outStride + c0;
            *(float4*)orow = make_float4(vv[0], vv[1], vv[2], vv[3]);
            *(float4*)(orow + 4) = make_float4(vv[4], vv[5], vv[6], vv[7]);
        }
    }
}

// ---------------- final: y = x@lin_w.T+lin_b+out2; out = relu(y@ln_w.T+ln_b)
__global__ __launch_bounds__(256) void final_mfma(
    const ushort* __restrict__ xb, const float* __restrict__ out2,
    const ushort* __restrict__ LWp, const float* __restrict__ lin_b,
    const ushort* __restrict__ NWp, const float* __restrict__ ln_b,
    float* __restrict__ out)
{
    __shared__ ushort ys[32][136];
    int t = threadIdx.x;
    int wave = t >> 6, lane = t & 63;
    int quad = lane >> 4, l16 = lane & 15;
    long row0 = (long)blockIdx.x * 32;
    int n0 = wave * 32;

    floatx4 zero = {0.f, 0.f, 0.f, 0.f};
    floatx4 acc[2][2];
#pragma unroll
    for (int mt = 0; mt < 2; mt++)
#pragma unroll
        for (int nt = 0; nt < 2; nt++) acc[mt][nt] = zero;

    for (int k0 = 0; k0 < HO; k0 += 32) {
        int kch = (k0 + quad * 8) >> 3;
        short8 a0 = *(const short8*)(xb + (long)kch * 65536 + (row0 + l16) * 8);
        short8 a1 = *(const short8*)(xb + (long)kch * 65536 + (row0 + 16 + l16) * 8);
        short8 b0 = *(const short8*)(LWp + kch * 1024 + (n0 + l16) * 8);
        short8 b1 = *(const short8*)(LWp + kch * 1024 + (n0 + 16 + l16) * 8);
        acc[0][0] = __builtin_amdgcn_mfma_f32_16x16x32_bf16(a0, b0, acc[0][0], 0, 0, 0);
        acc[0][1] = __builtin_amdgcn_mfma_f32_16x16x32_bf16(a0, b1, acc[0][1], 0, 0, 0);
        acc[1][0] = __builtin_amdgcn_mfma_f32_16x16x32_bf16(a1, b0, acc[1][0], 0, 0, 0);
        acc[1][1] = __builtin_amdgcn_mfma_f32_16x16x32_bf16(a1, b1, acc[1][1], 0, 0, 0);
    }

#pragma unroll
    for (int nt = 0; nt < 2; nt++) {
        int col = n0 + nt * 16 + l16;
        float lb = lin_b[col];
#pragma unroll
        for (int mt = 0; mt < 2; mt++) {
#pragma unroll
            for (int reg = 0; reg < 4; reg++) {
                int row = mt * 16 + quad * 4 + reg;
                float v = acc[mt][nt][reg] + lb + out2[(row0 + row) * OO + col];
                ys[row][col] = f2b(v);
            }
        }
    }
    __syncthreads();

    floatx4 acc2[2][2];
#pragma unroll
    for (int mt = 0; mt < 2; mt++)
#pragma unroll
        for (int nt = 0; nt < 2; nt++) acc2[mt][nt] = zero;

#pragma unroll
    for (int k0 = 0; k0 < OO; k0 += 32) {
        int kb = k0 + quad * 8;
        int kch = kb >> 3;
        short8 a0 = *(const short8*)&ys[l16][kb];
        short8 a1 = *(const short8*)&ys[16 + l16][kb];
        short8 b0 = *(const short8*)(NWp + kch * 1024 + (n0 + l16) * 8);
        short8 b1 = *(const short8*)(NWp + kch * 1024 + (n0 + 16 + l16) * 8);
        acc2[0][0] = __builtin_amdgcn_mfma_f32_16x16x32_bf16(a0, b0, acc2[0][0], 0, 0, 0);
        acc2[0][1] = __builtin_amdgcn_mfma_f32_16x16x32_bf16(a0, b1, acc2[0][1], 0, 0, 0);
        acc2[1][0] = __builtin_amdgcn_mfma_f32_16x16x32_bf16(a1, b0, acc2[1][0], 0, 0, 0);
        acc2[1][1] = __builtin_amdgcn_mfma_f32_16x16x32_bf16(a1, b1, acc2[1][1], 0, 0, 0);
    }

#pragma unroll
    for (int nt = 0; nt < 2; nt++) {
        int col = n0 + nt * 16 + l16;
        float nb = ln_b[col];
#pragma unroll
        for (int mt = 0; mt < 2; mt++) {
#pragma unroll
            for (int reg = 0; reg < 4; reg++) {
                int row = mt * 16 + quad * 4 + reg;
                out[(row0 + row) * OO + col] = fmaxf(acc2[mt][nt][reg] + nb, 0.f);
            }
        }
    }
}

extern "C" void kernel_launch(void* const* d_in, const int* in_sizes, int n_in,
                              void* d_out, int out_size, void* d_ws, size_t ws_size,
                              hipStream_t stream)
{
    const float* inputs = (const float*)d_in[0];
    const int*   adj    = (const int*)d_in[1];
    const float* W_att  = (const float*)d_in[3];
    const float* a_src  = (const float*)d_in[4];
    const float* a_dst  = (const float*)d_in[5];
    const float* W_out  = (const float*)d_in[6];
    const float* ao_src = (const float*)d_in[7];
    const float* ao_dst = (const float*)d_in[8];
    const float* lin_w  = (const float*)d_in[9];
    const float* lin_b  = (const float*)d_in[10];
    const float* ln_w   = (const float*)d_in[11];
    const float* ln_b   = (const float*)d_in[12];
    float* out = (float*)d_out;

    float* ws   = (float*)d_ws;
    float* out2 = ws;
    float* s1   = ws + 1048576;
    float* s2   = ws + 1114112;
    float* s1o  = ws + 1179648;
    float* s2o  = ws + 1187840;
    ushort* ub      = (ushort*)(ws + 1196032);
    ushort* x_b     = ub;
    ushort* h_catTb = ub + 8388608;
    ushort* h2Tb    = ub + 16777216;
    ushort* WAp     = ub + 17825792;
    ushort* WOp     = ub + 18087936;
    ushort* LWp     = ub + 18219008;
    ushort* NWp     = ub + 18350080;
    unsigned long long* adjp = (unsigned long long*)(ub + 18366464);

    const int SH = (NN + 8448 + 64) * 4;   // 38,144 B dyn LDS (attn)

    // 0. merged packing (adj bitmask + all weights)
    pack_all<<<2312, 256, 0, stream>>>(
        adj, adjp, W_att, W_out, lin_w, ln_w, WAp, WOp, LWp, NWp);
    // 1. h^T (packed f16) = (inputs @ W_att)^T per (b,h); fused s1/s2
    gemmT0<<<dim3(16, 64), 256, 0, stream>>>(
        WAp, inputs, h_catTb, s1, s2, a_src, a_dst);
    // 2. layer-0 attention -> x = elu(att@h) bf16, fragment-packed
    attn_mfma<2><<<dim3(16, 64), 256, SH, stream>>>(
        s1, s2, h_catTb, (const uint*)adjp, (float*)nullptr, x_b, HH, HO, 1, 1);
    // 3. h2^T (packed f16) = (x @ W_out)^T per b, split-K x4; fused s1o/s2o
    gemmT_sk<<<dim3(64, 8), 256, 0, stream>>>(
        WOp, x_b, h2Tb, s1o, s2o, ao_src, ao_dst);
    // 4. layer-1 attention -> out2 fp32 (no elu), j-split x4
    attn_mfma<4><<<dim3(64, 8), 256, SH, stream>>>(
        s1o, s2o, h2Tb, (const uint*)adjp, out2, (ushort*)nullptr, 1, OO, 0, 0);
    // 5. out = relu((x@lin_w.T + lin_b + out2) @ ln_w.T + ln_b)
    final_mfma<<<256, 256, 0, stream>>>(
        x_b, out2, LWp, lin_b, NWp, ln_b, out);
}